// Round 14
// baseline (1241.092 us; speedup 1.0000x reference)
//
#include <hip/hip_runtime.h>
#include <stdint.h>

#define Bb 128
#define Nn 1024
#define Dd 512
#define Ss 64

constexpr float kScale = 0.044194173824159216f;  // 512^-0.5
constexpr float kEps = 1e-8f;

typedef __bf16 bf16x8 __attribute__((ext_vector_type(8)));
typedef float f32x4 __attribute__((ext_vector_type(4)));
typedef float f32x16 __attribute__((ext_vector_type(16)));
typedef unsigned short ushort8 __attribute__((ext_vector_type(8)));

#define MFMA32 __builtin_amdgcn_mfma_f32_32x32x16_bf16

__device__ inline unsigned short f2bf_rne(float x) {
  unsigned u = __builtin_bit_cast(unsigned, x);
  u += 0x7FFFu + ((u >> 16) & 1u);
  return (unsigned short)(u >> 16);
}
__device__ inline float bf2f(unsigned short h) {
  unsigned u = ((unsigned)h) << 16;
  return __builtin_bit_cast(float, u);
}

// async global->LDS, 16B per lane; LDS dest must be wave-uniform base (HW adds lane*16)
__device__ inline void gl_lds16(const void* g, void* l) {
  typedef unsigned int u32;
  auto gp = (u32 __attribute__((address_space(1)))*)(unsigned long long)(uintptr_t)g;
  auto lp = (u32 __attribute__((address_space(3)))*)(unsigned int)(uintptr_t)l;
  __builtin_amdgcn_global_load_lds(gp, lp, 16, 0, 0);
}

// f32 -> INTERLEAVED split bf16: out[granule*16 + 0..7] = hi, [+8..15] = lo.
__global__ void cast_split_i(const float* __restrict__ in,
                             unsigned short* __restrict__ out, int n8) {
  int i = blockIdx.x * blockDim.x + threadIdx.x;
  const int stride = gridDim.x * blockDim.x;
  for (; i < n8; i += stride) {
    const float4 v0 = ((const float4*)in)[i * 2];
    const float4 v1 = ((const float4*)in)[i * 2 + 1];
    float f[8] = {v0.x, v0.y, v0.z, v0.w, v1.x, v1.y, v1.z, v1.w};
    ushort8 h, lo;
#pragma unroll
    for (int j = 0; j < 8; j++) {
      h[j] = f2bf_rne(f[j]);
      lo[j] = f2bf_rne(f[j] - bf2f(h[j]));
    }
    ((ushort8*)out)[i * 2] = h;
    ((ushort8*)out)[i * 2 + 1] = lo;
  }
}

// C[M,512] = act(A[M,512] @ W[512,512]^T + bias), FUSED 3-term split bf16.
// Interleaved split layout [row][1024 ushorts], granule g at g*16 (+0 hi, +8 lo).
// R14: WAVE-AUTONOMOUS. 4 waves/block, each wave owns a PRIVATE 128x64 output
// tile and a PRIVATE ring-3 x 12KB LDS region (A-slab 128x[32u] + W-slab
// 64x[32u] per K-half of 16). ZERO barriers: per-wave counted vmcnt(12)
// (stage depth 2) and counted lgkmcnt(12) (frag reads drain under MFMA via
// register double-buffer). No cross-wave data -> no race surface.
// Swizzle (R13-proven): stored 16B piece p = q ^ ((row>>1)&3); frag read
// ppA = ((2*(l>>5)) ^ ((l>>1)&3))*8, lo at ^8; staging source piece
// qs = (l&3) ^ ((l>>3)&3) (involution), linear LDS dest.
template <int ACT>
__global__ __launch_bounds__(256, 1) void gemm_wa(
    const unsigned short* __restrict__ A, const unsigned short* __restrict__ W,
    const float* __restrict__ bias, unsigned short* __restrict__ C) {
  constexpr int NH = 32;  // K=512 / 16
  extern __shared__ unsigned short lds[];  // 4 waves x 3 slots x 6144 ushorts = 144KB
  const int t = threadIdx.x, l = t & 63, w = t >> 6;
  const int wr = w >> 1, wc = w & 1;

  // bijective XCD-chunked swizzle (2048 = 8 x 256)
  const int wg = ((blockIdx.x & 7) << 8) + (blockIdx.x >> 3);
  const long rowA0 = (long)(wg >> 2) * 256;
  const int colB0 = (wg & 3) * 128;
  unsigned short* wlds = lds + w * 18432;  // private 36KB region

  // ---- private staging: 12 chunks/half (16 rows x 64B each) ----
  // c<8: A rows (rowA0 + wr*128) + c*16+(l>>2); c>=8: W rows (colB0+wc*64)+...
  const unsigned short* Abase = A + (rowA0 + wr * 128) * 1024;
  const unsigned short* Wbase = W + (long)(colB0 + wc * 64) * 1024;
  const int qs = (l & 3) ^ ((l >> 3) & 3);
  const unsigned short* srcp[12];
  int dstp[12];
#pragma unroll
  for (int c = 0; c < 12; c++) {
    const int rrel = (c < 8 ? c : c - 8) * 16 + (l >> 2);
    srcp[c] = (c < 8 ? Abase : Wbase) + (long)rrel * 1024 + qs * 8;
    dstp[c] = c * 512;  // + lane*8 implicit
  }
#define STG(h)                                                            \
  {                                                                       \
    unsigned short* bq_ = wlds + ((h) % 3) * 6144;                        \
    _Pragma("unroll") for (int c = 0; c < 12; c++)                        \
        gl_lds16(srcp[c] + (h) * 32, bq_ + dstp[c]);                      \
  }

  // ---- frag reads (private slab): row = m*32 + (l&31); A @0, W @4096u ----
  const int ppA = ((2 * (l >> 5)) ^ ((l >> 1) & 3)) * 8;
  int aoff[4], boff[2];
#pragma unroll
  for (int m = 0; m < 4; m++) aoff[m] = (m * 32 + (l & 31)) * 32 + ppA;
#pragma unroll
  for (int n = 0; n < 2; n++) boff[n] = 4096 + (n * 32 + (l & 31)) * 32 + ppA;

#define READF(h, S)                                                       \
  {                                                                       \
    const unsigned short* bq_ = wlds + ((h) % 3) * 6144;                  \
    _Pragma("unroll") for (int m = 0; m < 4; m++) {                       \
      ah##S[m] = *(const bf16x8*)(bq_ + aoff[m]);                         \
      al##S[m] = *(const bf16x8*)(bq_ + (aoff[m] ^ 8));                   \
    }                                                                     \
    _Pragma("unroll") for (int n = 0; n < 2; n++) {                       \
      bh##S[n] = *(const bf16x8*)(bq_ + boff[n]);                         \
      bl##S[n] = *(const bf16x8*)(bq_ + (boff[n] ^ 8));                   \
    }                                                                     \
  }

#define MFMACL(S)                                                         \
  {                                                                       \
    _Pragma("unroll") for (int m = 0; m < 4; m++)                         \
        _Pragma("unroll") for (int n = 0; n < 2; n++) {                   \
      acc[m][n] = MFMA32(ah##S[m], bh##S[n], acc[m][n], 0, 0, 0);         \
      acc[m][n] = MFMA32(al##S[m], bh##S[n], acc[m][n], 0, 0, 0);         \
      acc[m][n] = MFMA32(ah##S[m], bl##S[n], acc[m][n], 0, 0, 0);         \
    }                                                                     \
  }

  // Per-iter h (no barriers, all per-wave):
  //   STG(h+2)                         [12 gl_lds into slot last read at h-1]
  //   vmcnt(12)                        [stage(h+1) landed; h+2's 12 in flight]
  //   READF(h+1) -> other reg set      [12 ds_read, drain under MFMA(h)]
  //   lgkmcnt(12) + sched_barrier      [frags(h) landed; h+1 reads in flight]
  //   setprio(1); 24 MFMA(h); setprio(0)
#define BODY(h, CUR, NXT)                                                 \
  {                                                                       \
    if ((h) + 2 < NH) STG((h) + 2);                                       \
    if ((h) + 1 < NH) {                                                   \
      if ((h) + 2 < NH) {                                                 \
        asm volatile("s_waitcnt vmcnt(12)" ::: "memory");                 \
      } else {                                                            \
        asm volatile("s_waitcnt vmcnt(0)" ::: "memory");                  \
      }                                                                   \
      READF((h) + 1, NXT);                                                \
      asm volatile("s_waitcnt lgkmcnt(12)" ::: "memory");                 \
    } else {                                                              \
      asm volatile("s_waitcnt lgkmcnt(0)" ::: "memory");                  \
    }                                                                     \
    __builtin_amdgcn_sched_barrier(0);                                    \
    __builtin_amdgcn_s_setprio(1);                                        \
    MFMACL(CUR);                                                          \
    __builtin_amdgcn_s_setprio(0);                                        \
  }

  f32x16 acc[4][2] = {};
  bf16x8 ahA[4], alA[4], bhA[2], blA[2];
  bf16x8 ahB[4], alB[4], bhB[2], blB[2];

  STG(0);
  STG(1);
  asm volatile("s_waitcnt vmcnt(12)" ::: "memory");  // stage(0) landed
  READF(0, A);

#pragma unroll
  for (int hh = 0; hh < NH; hh += 2) {
    BODY(hh, A, B);
    BODY(hh + 1, B, A);
  }
#undef STG
#undef READF
#undef MFMACL
#undef BODY

  // epilogue: C/D 32x32 layout: col = l&31, row = (r&3)+8*(r>>2)+4*(l>>5);
  // interleaved write: hi at row*1024 + (col>>3)*16 + (col&7), lo at +8.
#pragma unroll
  for (int m = 0; m < 4; m++)
#pragma unroll
    for (int n = 0; n < 2; n++) {
      const int col = colB0 + wc * 64 + n * 32 + (l & 31);
      const float bv = bias[col];
      const int cofs = (col >> 3) * 16 + (col & 7);
#pragma unroll
      for (int r = 0; r < 16; r++) {
        const long row = rowA0 + wr * 128 + m * 32 + (r & 3) + 8 * (r >> 2) + 4 * (l >> 5);
        float xv = acc[m][n][r] + bv;
        if (ACT) xv = fmaxf(xv, 0.0f);
        const unsigned short h = f2bf_rne(xv);
        unsigned short* cp = C + row * 1024 + cofs;
        cp[0] = h;
        cp[8] = f2bf_rne(xv - bf2f(h));
      }
    }
}

// dots[b,64,1024] = scale * slots[64,512] @ k[b,1024,512]^T  (interleaved split in)
__global__ __launch_bounds__(256) void gemm_dots_split(
    const unsigned short* __restrict__ QI, const unsigned short* __restrict__ KI,
    float* __restrict__ dots) {
  constexpr int K = 512, BM = 64, BN = 128, BK = 32;
  __shared__ __align__(16) unsigned short lah[BM * BK];
  __shared__ __align__(16) unsigned short lal[BM * BK];
  __shared__ __align__(16) unsigned short lbh[BN * BK];
  __shared__ __align__(16) unsigned short lbl[BN * BK];
  const int t = threadIdx.x, l = t & 63, w = t >> 6;
  const int b = blockIdx.x >> 3, bc = blockIdx.x & 7;
  const unsigned short* kb = KI + (long)b * Nn * 1024;
  f32x4 acc[4][2] = {};

  const int qbase = (t >> 2) * 1024 + (t & 3) * 16;
  const long kbase0 = (long)(bc * BN + (t >> 2)) * 1024 + (t & 3) * 16;
  const long kbase1 = (long)(bc * BN + 64 + (t >> 2)) * 1024 + (t & 3) * 16;

  for (int k0 = 0; k0 < K; k0 += BK) {
    const int ko = k0 * 2;  // ushort offset of granule (k0>>3)*16
    const int lo = w * 512;
    gl_lds16(QI + qbase + ko, lah + lo);
    gl_lds16(QI + qbase + ko + 8, lal + lo);
    gl_lds16(kb + kbase0 + ko, lbh + lo);
    gl_lds16(kb + kbase0 + ko + 8, lbl + lo);
    gl_lds16(kb + kbase1 + ko, lbh + 2048 + lo);
    gl_lds16(kb + kbase1 + ko + 8, lbl + 2048 + lo);
    __syncthreads();
    bf16x8 ah[4], al[4], bh[2], bl[2];
#pragma unroll
    for (int m = 0; m < 4; m++) {
      const int off = (m * 16 + (l & 15)) * BK + (l >> 4) * 8;
      ah[m] = *(const bf16x8*)(lah + off);
      al[m] = *(const bf16x8*)(lal + off);
    }
#pragma unroll
    for (int n = 0; n < 2; n++) {
      const int off = (w * 32 + n * 16 + (l & 15)) * BK + (l >> 4) * 8;
      bh[n] = *(const bf16x8*)(lbh + off);
      bl[n] = *(const bf16x8*)(lbl + off);
    }
#pragma unroll
    for (int m = 0; m < 4; m++)
#pragma unroll
      for (int n = 0; n < 2; n++) {
        acc[m][n] = __builtin_amdgcn_mfma_f32_16x16x32_bf16(ah[m], bh[n], acc[m][n], 0, 0, 0);
        acc[m][n] = __builtin_amdgcn_mfma_f32_16x16x32_bf16(al[m], bh[n], acc[m][n], 0, 0, 0);
        acc[m][n] = __builtin_amdgcn_mfma_f32_16x16x32_bf16(ah[m], bl[n], acc[m][n], 0, 0, 0);
      }
    __syncthreads();
  }
  float* dp = dots + (long)b * Ss * Nn;
#pragma unroll
  for (int m = 0; m < 4; m++) {
    const int row = m * 16 + (l >> 4) * 4;
#pragma unroll
    for (int n = 0; n < 2; n++) {
      const int col = bc * BN + w * 32 + n * 16 + (l & 15);
#pragma unroll
      for (int r = 0; r < 4; r++) dp[(long)(row + r) * Nn + col] = acc[m][n][r] * kScale;
    }
  }
}

// per-batch: s_j[b,i] = sum_j dots, s_all[b] = sum_ij dots (coalesced float4 + shfl)
__global__ __launch_bounds__(256) void reduce_k(
    const float* __restrict__ dots, float* __restrict__ s_j, float* __restrict__ s_all) {
  const int b = blockIdx.x, t = threadIdx.x, l = t & 63, w = t >> 6;
  const float4* dp = (const float4*)(dots + (long)b * Ss * Nn);
  __shared__ float rowacc[64][4];
  __shared__ float rowsum[64];
  for (int r = 0; r < 64; ++r) {
    const float4 v = dp[r * 256 + t];
    float s = v.x + v.y + v.z + v.w;
#pragma unroll
    for (int off = 32; off; off >>= 1) s += __shfl_down(s, off);
    if (l == 0) rowacc[r][w] = s;
  }
  __syncthreads();
  if (t < 64) {
    const float v = rowacc[t][0] + rowacc[t][1] + rowacc[t][2] + rowacc[t][3];
    rowsum[t] = v;
    s_j[b * 64 + t] = v;
  }
  __syncthreads();
  if (t < 64) {
    float v = rowsum[t];
#pragma unroll
    for (int off = 32; off; off >>= 1) v += __shfl_down(v, off);
    if (t == 0) s_all[b] = v;
  }
}

// attn = sigmoid(dots * s_all/s_j) -> out; inv_r = 1/(rowsum(attn)+eps)
__global__ __launch_bounds__(256) void attn_k(
    const float* __restrict__ dots, const float* __restrict__ s_j,
    const float* __restrict__ s_all, float* __restrict__ attn_out,
    float* __restrict__ inv_r) {
  const int bi = blockIdx.x;
  const int b = bi >> 6;
  const int t = threadIdx.x;
  const float ratio = s_all[b] / s_j[bi];
  const float* dp = dots + (long)bi * Nn;
  float* ap = attn_out + (long)bi * Nn;
  float s = 0.f;
#pragma unroll
  for (int qq = 0; qq < 4; qq++) {
    const int j = qq * 256 + t;
    const float x = dp[j] * ratio;
    const float a = 1.f / (1.f + expf(-x));
    ap[j] = a;
    s += a;
  }
  __shared__ float red[256];
  red[t] = s;
  __syncthreads();
  for (int off = 128; off > 0; off >>= 1) {
    if (t < off) red[t] += red[t + off];
    __syncthreads();
  }
  if (t == 0) inv_r[bi] = 1.f / (red[0] + kEps);
}

// updates[b,i,d] = inv_r[b,i] * sum_j attn[b,i,j] * inputs[b,j,d]  (fp32 register tile)
__global__ __launch_bounds__(256, 1) void updates_k2(
    const float* __restrict__ attn, const float* __restrict__ inputs,
    const float* __restrict__ inv_r, float* __restrict__ out0) {
  constexpr int NT2 = 32;
  constexpr int BUF_F = 10240;
  extern __shared__ float ldsf[];
  const int t = threadIdx.x, lam = t & 63, w = t >> 6;
  const int b = blockIdx.x >> 1, dt = blockIdx.x & 1;
  const int ig = t >> 5, dg = t & 31;
  const float* inb = inputs + (size_t)b * (Nn * Dd) + dt * 256;
  const float* attsrc = attn + (size_t)b * (Ss * Nn) + (size_t)(t >> 2) * Nn + (t & 3) * 8;
  float acc[8][8] = {};
  float4 ga0, ga1, gb0, gb1;

#define UISSUE(bufi, tile, G0, G1)                                        \
  {                                                                       \
    const int j0_ = (tile)*32;                                            \
    G0 = *(const float4*)(attsrc + j0_);                                  \
    G1 = *(const float4*)(attsrc + j0_ + 4);                              \
    float* db_ = ldsf + (bufi)*BUF_F;                                     \
    _Pragma("unroll") for (int i_ = 0; i_ < 8; i_++) {                    \
      const int row_ = i_ * 4 + w;                                        \
      gl_lds16(inb + (size_t)(j0_ + row_) * Dd + lam * 4, db_ + row_ * 256); \
    }                                                                     \
  }

#define UWRITE(bufi, G0, G1)                                              \
  {                                                                       \
    float* ab_ = ldsf + (bufi)*BUF_F + 8192;                              \
    const int col_ = t >> 2;                                              \
    const int r0_ = (t & 3) * 8;                                          \
    ab_[(r0_ + 0) * 64 + col_] = G0.x;                                    \
    ab_[(r0_ + 1) * 64 + col_] = G0.y;                                    \
    ab_[(r0_ + 2) * 64 + col_] = G0.z;                                    \
    ab_[(r0_ + 3) * 64 + col_] = G0.w;                                    \
    ab_[(r0_ + 4) * 64 + col_] = G1.x;                                    \
    ab_[(r0_ + 5) * 64 + col_] = G1.y;                                    \
    ab_[(r0_ + 6) * 64 + col_] = G1.z;                                    \
    ab_[(r0_ + 7) * 64 + col_] = G1.w;                                    \
  }

#define UCOMP(bufi)                                                       \
  {                                                                       \
    const float* db_ = ldsf + (bufi)*BUF_F;                               \
    const float* ab_ = db_ + 8192;                                        \
    _Pragma("unroll 4") for (int jj = 0; jj < 32; jj++) {                 \
      float av[8], vv[8];                                                 \
      *(float4*)&av[0] = *(const float4*)(ab_ + jj * 64 + ig * 8);        \
      *(float4*)&av[4] = *(const float4*)(ab_ + jj * 64 + ig * 8 + 4);    \
      *(float4*)&vv[0] = *(const float4*)(db_ + jj * 256 + dg * 8);       \
      *(float4*)&vv[4] = *(const float4*)(db_ + jj * 256 + dg * 8 + 4);   \
      _Pragma("unroll") for (int m_ = 0; m_ < 8; m_++)                    \
          _Pragma("unroll") for (int n_ = 0; n_ < 8; n_++)                \
              acc[m_][n_] = __builtin_fmaf(av[m_], vv[n_], acc[m_][n_]);  \
    }                                                                     \
  }

  UISSUE(0, 0, ga0, ga1);
  UISSUE(1, 1, gb0, gb1);
  UWRITE(0, ga0, ga1);

  for (int tt = 0; tt < NT2; tt += 2) {
    asm volatile("s_waitcnt vmcnt(10)" ::: "memory");
    UWRITE((tt + 1) % 3, gb0, gb1);
    asm volatile("s_waitcnt lgkmcnt(0)" ::: "memory");
    __builtin_amdgcn_s_barrier();
    __builtin_amdgcn_sched_barrier(0);
    if (tt < NT2 - 2) UISSUE((tt + 2) % 3, tt + 2, ga0, ga1);
    UCOMP(tt % 3);
    if (tt + 1 < NT2 - 1) {
      asm volatile("s_waitcnt vmcnt(10)" ::: "memory");
    } else {
      asm volatile("s_waitcnt vmcnt(0)" ::: "memory");
    }
    if (tt + 1 < NT2 - 1) UWRITE((tt + 2) % 3, ga0, ga1);
    asm volatile("s_waitcnt lgkmcnt(0)" ::: "memory");
    __builtin_amdgcn_s_barrier();
    __builtin_amdgcn_sched_barrier(0);
    if (tt + 1 < NT2 - 2) UISSUE((tt + 3) % 3, tt + 3, gb0, gb1);
    UCOMP((tt + 1) % 3);
  }
#undef UISSUE
#undef UWRITE
#undef UCOMP

#pragma unroll
  for (int m = 0; m < 8; m++) {
    const int i = ig * 8 + m;
    const float ir = inv_r[b * 64 + i];
    float4 o0, o1;
    o0.x = acc[m][0] * ir; o0.y = acc[m][1] * ir; o0.z = acc[m][2] * ir; o0.w = acc[m][3] * ir;
    o1.x = acc[m][4] * ir; o1.y = acc[m][5] * ir; o1.z = acc[m][6] * ir; o1.w = acc[m][7] * ir;
    float* op = out0 + (size_t)(b * 64 + i) * Dd + dt * 256 + dg * 8;
    *(float4*)op = o0;
    *(float4*)(op + 4) = o1;
  }
}

extern "C" void kernel_launch(void* const* d_in, const int* in_sizes, int n_in,
                              void* d_out, int out_size, void* d_ws, size_t ws_size,
                              hipStream_t stream) {
  (void)in_sizes; (void)n_in; (void)out_size; (void)ws_size;
  const float* inputs_pe = (const float*)d_in[0];
  const float* inputs = (const float*)d_in[1];
  const float* slots = (const float*)d_in[2];
  const float* W1 = (const float*)d_in[3];
  const float* b1 = (const float*)d_in[4];
  const float* W2 = (const float*)d_in[5];
  const float* b2 = (const float*)d_in[6];
  const float* W3 = (const float*)d_in[7];
  const float* b3 = (const float*)d_in[8];

  char* ws = (char*)d_ws;
  size_t off = 0;
  auto alloc = [&](size_t bytes) -> void* {
    void* p = ws + off;
    off += (bytes + 255) & ~(size_t)255;
    return p;
  };
  const size_t actB = (size_t)Bb * Nn * 1024 * 2;  // interleaved split activation
  unsigned short* AI = (unsigned short*)alloc(actB);
  unsigned short* BI = (unsigned short*)alloc(actB);
  unsigned short* w1i = (unsigned short*)alloc(Dd * 1024 * 2);
  unsigned short* w2i = (unsigned short*)alloc(Dd * 1024 * 2);
  unsigned short* w3i = (unsigned short*)alloc(Dd * 1024 * 2);
  unsigned short* qi = (unsigned short*)alloc(Ss * 1024 * 2);
  float* dotsb = (float*)alloc((size_t)Bb * Ss * Nn * 4);
  float* s_j = (float*)alloc(Bb * Ss * 4);
  float* s_all = (float*)alloc(Bb * 4);
  float* inv_r = (float*)alloc(Bb * Ss * 4);

  float* out_updates = (float*)d_out;
  float* out_attn = out_updates + (size_t)Bb * Ss * Dd;

  const int kLdsG = 144 * 1024;     // 4 waves x ring-3 x 12KB
  const int kLdsU = 3 * 40 * 1024;  // 120KB for updates_k2
  hipFuncSetAttribute(reinterpret_cast<const void*>(gemm_wa<1>),
                      hipFuncAttributeMaxDynamicSharedMemorySize, kLdsG);
  hipFuncSetAttribute(reinterpret_cast<const void*>(gemm_wa<0>),
                      hipFuncAttributeMaxDynamicSharedMemorySize, kLdsG);
  hipFuncSetAttribute(reinterpret_cast<const void*>(updates_k2),
                      hipFuncAttributeMaxDynamicSharedMemorySize, kLdsU);

  cast_split_i<<<4096, 256, 0, stream>>>(inputs_pe, AI, Bb * Nn * Dd / 8);
  cast_split_i<<<128, 256, 0, stream>>>(W1, w1i, Dd * Dd / 8);
  cast_split_i<<<128, 256, 0, stream>>>(W2, w2i, Dd * Dd / 8);
  cast_split_i<<<128, 256, 0, stream>>>(W3, w3i, Dd * Dd / 8);
  cast_split_i<<<16, 256, 0, stream>>>(slots, qi, Ss * Dd / 8);

  gemm_wa<1><<<2048, 256, kLdsG, stream>>>(AI, w1i, b1, BI);
  gemm_wa<1><<<2048, 256, kLdsG, stream>>>(BI, w2i, b2, AI);
  gemm_wa<0><<<2048, 256, kLdsG, stream>>>(AI, w3i, b3, BI);

  gemm_dots_split<<<Bb * 8, 256, 0, stream>>>(qi, BI, dotsb);
  reduce_k<<<Bb, 256, 0, stream>>>(dotsb, s_j, s_all);
  attn_k<<<Bb * Ss, 256, 0, stream>>>(dotsb, s_j, s_all, out_attn, inv_r);
  updates_k2<<<Bb * 2, 256, kLdsU, stream>>>(out_attn, inputs, inv_r, out_updates);
}

// Round 15
// 1183.970 us; speedup vs baseline: 1.0482x; 1.0482x over previous
//
#include <hip/hip_runtime.h>
#include <stdint.h>

#define Bb 128
#define Nn 1024
#define Dd 512
#define Ss 64

constexpr float kScale = 0.044194173824159216f;  // 512^-0.5
constexpr float kEps = 1e-8f;

typedef __bf16 bf16x8 __attribute__((ext_vector_type(8)));
typedef float f32x4 __attribute__((ext_vector_type(4)));
typedef float f32x16 __attribute__((ext_vector_type(16)));
typedef unsigned short ushort8 __attribute__((ext_vector_type(8)));

#define MFMA32 __builtin_amdgcn_mfma_f32_32x32x16_bf16

__device__ inline unsigned short f2bf_rne(float x) {
  unsigned u = __builtin_bit_cast(unsigned, x);
  u += 0x7FFFu + ((u >> 16) & 1u);
  return (unsigned short)(u >> 16);
}
__device__ inline float bf2f(unsigned short h) {
  unsigned u = ((unsigned)h) << 16;
  return __builtin_bit_cast(float, u);
}

// async global->LDS, 16B per lane; LDS dest must be wave-uniform base (HW adds lane*16)
__device__ inline void gl_lds16(const void* g, void* l) {
  typedef unsigned int u32;
  auto gp = (u32 __attribute__((address_space(1)))*)(unsigned long long)(uintptr_t)g;
  auto lp = (u32 __attribute__((address_space(3)))*)(unsigned int)(uintptr_t)l;
  __builtin_amdgcn_global_load_lds(gp, lp, 16, 0, 0);
}

// f32 -> INTERLEAVED split bf16: out[granule*16 + 0..7] = hi, [+8..15] = lo.
__global__ void cast_split_i(const float* __restrict__ in,
                             unsigned short* __restrict__ out, int n8) {
  int i = blockIdx.x * blockDim.x + threadIdx.x;
  const int stride = gridDim.x * blockDim.x;
  for (; i < n8; i += stride) {
    const float4 v0 = ((const float4*)in)[i * 2];
    const float4 v1 = ((const float4*)in)[i * 2 + 1];
    float f[8] = {v0.x, v0.y, v0.z, v0.w, v1.x, v1.y, v1.z, v1.w};
    ushort8 h, lo;
#pragma unroll
    for (int j = 0; j < 8; j++) {
      h[j] = f2bf_rne(f[j]);
      lo[j] = f2bf_rne(f[j] - bf2f(h[j]));
    }
    ((ushort8*)out)[i * 2] = h;
    ((ushort8*)out)[i * 2 + 1] = lo;
  }
}

// C[M,512] = act(A[M,512] @ W[512,512]^T + bias), FUSED 3-term split bf16.
// Interleaved split layout [row][1024 ushorts], granule g at g*16 (+0 hi, +8 lo).
// R15: 128x128 tile, 8 waves (2Mx4N) of 64x32, 32x32x16 MFMA, K-half = 16.
// Ring-4 x 16KB LDS (half slot: A[128][32u] @0 | W[128][32u] @4096u).
// acc 32 AGPR + dbuf frags 48 -> ~110 VGPR; launch_bounds(512,4) ->
// 2 blocks/CU = 16 waves/CU = 4 waves/SIMD: two INDEPENDENT barrier groups
// per CU overlap each other's convoy gaps (m114 mechanism) - the one
// occupancy point never tested in R3-R14 (all were 8 waves/CU).
// Schedule/gate order verbatim from race-proven R11: lgkmcnt(0); vmcnt(counted,
// BEFORE barrier); s_barrier; STG(h+4); READF(h+1)->other reg set; sched_bar;
// setprio(1) 6xMFMA setprio(0). vmcnt thresholds rescaled for 2 loads/stage.
// Swizzle (R11/R13-refcheck-proven): stored 16B piece p = q ^ ((row>>1)&3);
// frag read ppA = ((2*(l>>5)) ^ ((l>>1)&3))*8, lo at ^8; staging source
// qs = (l&3)^((l>>3)&3), linear LDS dest.
template <int ACT>
__global__ __launch_bounds__(512, 4) void gemm_2b(
    const unsigned short* __restrict__ A, const unsigned short* __restrict__ W,
    const float* __restrict__ bias, unsigned short* __restrict__ C) {
  constexpr int NH = 32;  // K=512 / 16
  extern __shared__ unsigned short lds[];  // 4 x 8192 ushorts = 64KB
  const int t = threadIdx.x, l = t & 63, w = t >> 6;
  const int wr = w >> 2, wc = w & 3;

  // bijective XCD-chunked swizzle (4096 = 8 x 512); 4 consecutive wg share A panel
  const int wg = ((blockIdx.x & 7) << 9) + (blockIdx.x >> 3);
  const long rowA0 = (long)(wg >> 2) * 128;
  const int colB0 = (wg & 3) * 128;

  // ---- staging: 16 chunks/slot (16 rows x 64B each); 2 per wave ----
  // cid<8: A rows cid*16+(l>>2); cid>=8: W rows (cid-8)*16+(l>>2).
  // dest piece l&3 (linear), source piece qs = (l&3)^((l>>3)&3).
  const int qs = (l & 3) ^ ((l >> 3) & 3);
  const unsigned short* srcp[2];
  int dstp[2];
#pragma unroll
  for (int j = 0; j < 2; j++) {
    const int cid = w * 2 + j;  // 0..15
    const unsigned short* base =
        (cid < 8) ? A + rowA0 * 1024 : W + (long)colB0 * 1024;
    const int rrel = (cid & 7) * 16 + (l >> 2);
    srcp[j] = base + (long)rrel * 1024 + qs * 8;
    dstp[j] = cid * 512;  // + lane*8 implicit
  }
#define STG(h)                                                            \
  {                                                                       \
    unsigned short* bq_ = lds + ((h) & 3) * 8192;                         \
    _Pragma("unroll") for (int j = 0; j < 2; j++)                         \
        gl_lds16(srcp[j] + (h) * 32, bq_ + dstp[j]);                      \
  }

  // ---- frag reads: row = R0+(l&31) (R0 mult of 32), granule g = l>>5;
  // hi piece = 2g stored at (2g)^((l>>1)&3); lo at ^8. A @0, W @4096u. ----
  const int ppA = ((2 * (l >> 5)) ^ ((l >> 1) & 3)) * 8;
  int aoff[2];
#pragma unroll
  for (int m = 0; m < 2; m++) aoff[m] = (wr * 64 + m * 32 + (l & 31)) * 32 + ppA;
  const int boff = 4096 + (wc * 32 + (l & 31)) * 32 + ppA;

#define READF(h, S)                                                       \
  {                                                                       \
    const unsigned short* bq_ = lds + ((h) & 3) * 8192;                   \
    _Pragma("unroll") for (int m = 0; m < 2; m++) {                       \
      ah##S[m] = *(const bf16x8*)(bq_ + aoff[m]);                         \
      al##S[m] = *(const bf16x8*)(bq_ + (aoff[m] ^ 8));                   \
    }                                                                     \
    bh##S = *(const bf16x8*)(bq_ + boff);                                 \
    bl##S = *(const bf16x8*)(bq_ + (boff ^ 8));                           \
  }

#define MFMACL(S)                                                         \
  {                                                                       \
    _Pragma("unroll") for (int m = 0; m < 2; m++) {                       \
      acc[m] = MFMA32(ah##S[m], bh##S, acc[m], 0, 0, 0);                  \
      acc[m] = MFMA32(al##S[m], bh##S, acc[m], 0, 0, 0);                  \
      acc[m] = MFMA32(ah##S[m], bl##S, acc[m], 0, 0, 0);                  \
    }                                                                     \
  }

#define BODY(h, CUR, NXT)                                                 \
  {                                                                       \
    asm volatile("s_waitcnt lgkmcnt(0)" ::: "memory");                    \
    __builtin_amdgcn_sched_barrier(0);                                    \
    if ((h) < 29) {                                                       \
      asm volatile("s_waitcnt vmcnt(4)" ::: "memory");                    \
    } else if ((h) == 29) {                                               \
      asm volatile("s_waitcnt vmcnt(2)" ::: "memory");                    \
    } else if ((h) == 30) {                                               \
      asm volatile("s_waitcnt vmcnt(0)" ::: "memory");                    \
    }                                                                     \
    __builtin_amdgcn_s_barrier();                                         \
    if ((h) + 4 < NH) STG((h) + 4);                                       \
    if ((h) + 1 < NH) READF((h) + 1, NXT);                                \
    __builtin_amdgcn_sched_barrier(0);                                    \
    __builtin_amdgcn_s_setprio(1);                                        \
    MFMACL(CUR);                                                          \
    __builtin_amdgcn_s_setprio(0);                                        \
  }

  f32x16 acc[2] = {};
  bf16x8 ahA[2], alA[2], bhA, blA;
  bf16x8 ahB[2], alB[2], bhB, blB;

  STG(0); STG(1); STG(2); STG(3);
  asm volatile("s_waitcnt vmcnt(6)" ::: "memory");   // own stage(0) landed
  __builtin_amdgcn_s_barrier();                      // everyone's stage(0) landed
  READF(0, A);

  for (int hh = 0; hh < NH; hh += 2) {
    BODY(hh, A, B);
    BODY(hh + 1, B, A);
  }
#undef STG
#undef READF
#undef MFMACL
#undef BODY

  // epilogue (R11 style): C/D 32x32: col = l&31, row = (r&3)+8*(r>>2)+4*(l>>5);
  // interleaved write: hi at row*1024 + (col>>3)*16 + (col&7), lo at +8.
#pragma unroll
  for (int m = 0; m < 2; m++) {
    const int col = colB0 + wc * 32 + (l & 31);
    const float bv = bias[col];
    const int cofs = (col >> 3) * 16 + (col & 7);
#pragma unroll
    for (int r = 0; r < 16; r++) {
      const long row = rowA0 + wr * 64 + m * 32 + (r & 3) + 8 * (r >> 2) + 4 * (l >> 5);
      float xv = acc[m][r] + bv;
      if (ACT) xv = fmaxf(xv, 0.0f);
      const unsigned short h = f2bf_rne(xv);
      unsigned short* cp = C + row * 1024 + cofs;
      cp[0] = h;
      cp[8] = f2bf_rne(xv - bf2f(h));
    }
  }
}

// dots[b,64,1024] = scale * slots[64,512] @ k[b,1024,512]^T  (interleaved split in)
__global__ __launch_bounds__(256) void gemm_dots_split(
    const unsigned short* __restrict__ QI, const unsigned short* __restrict__ KI,
    float* __restrict__ dots) {
  constexpr int K = 512, BM = 64, BN = 128, BK = 32;
  __shared__ __align__(16) unsigned short lah[BM * BK];
  __shared__ __align__(16) unsigned short lal[BM * BK];
  __shared__ __align__(16) unsigned short lbh[BN * BK];
  __shared__ __align__(16) unsigned short lbl[BN * BK];
  const int t = threadIdx.x, l = t & 63, w = t >> 6;
  const int b = blockIdx.x >> 3, bc = blockIdx.x & 7;
  const unsigned short* kb = KI + (long)b * Nn * 1024;
  f32x4 acc[4][2] = {};

  const int qbase = (t >> 2) * 1024 + (t & 3) * 16;
  const long kbase0 = (long)(bc * BN + (t >> 2)) * 1024 + (t & 3) * 16;
  const long kbase1 = (long)(bc * BN + 64 + (t >> 2)) * 1024 + (t & 3) * 16;

  for (int k0 = 0; k0 < K; k0 += BK) {
    const int ko = k0 * 2;  // ushort offset of granule (k0>>3)*16
    const int lo = w * 512;
    gl_lds16(QI + qbase + ko, lah + lo);
    gl_lds16(QI + qbase + ko + 8, lal + lo);
    gl_lds16(kb + kbase0 + ko, lbh + lo);
    gl_lds16(kb + kbase0 + ko + 8, lbl + lo);
    gl_lds16(kb + kbase1 + ko, lbh + 2048 + lo);
    gl_lds16(kb + kbase1 + ko + 8, lbl + 2048 + lo);
    __syncthreads();
    bf16x8 ah[4], al[4], bh[2], bl[2];
#pragma unroll
    for (int m = 0; m < 4; m++) {
      const int off = (m * 16 + (l & 15)) * BK + (l >> 4) * 8;
      ah[m] = *(const bf16x8*)(lah + off);
      al[m] = *(const bf16x8*)(lal + off);
    }
#pragma unroll
    for (int n = 0; n < 2; n++) {
      const int off = (w * 32 + n * 16 + (l & 15)) * BK + (l >> 4) * 8;
      bh[n] = *(const bf16x8*)(lbh + off);
      bl[n] = *(const bf16x8*)(lbl + off);
    }
#pragma unroll
    for (int m = 0; m < 4; m++)
#pragma unroll
      for (int n = 0; n < 2; n++) {
        acc[m][n] = __builtin_amdgcn_mfma_f32_16x16x32_bf16(ah[m], bh[n], acc[m][n], 0, 0, 0);
        acc[m][n] = __builtin_amdgcn_mfma_f32_16x16x32_bf16(al[m], bh[n], acc[m][n], 0, 0, 0);
        acc[m][n] = __builtin_amdgcn_mfma_f32_16x16x32_bf16(ah[m], bl[n], acc[m][n], 0, 0, 0);
      }
    __syncthreads();
  }
  float* dp = dots + (long)b * Ss * Nn;
#pragma unroll
  for (int m = 0; m < 4; m++) {
    const int row = m * 16 + (l >> 4) * 4;
#pragma unroll
    for (int n = 0; n < 2; n++) {
      const int col = bc * BN + w * 32 + n * 16 + (l & 15);
#pragma unroll
      for (int r = 0; r < 4; r++) dp[(long)(row + r) * Nn + col] = acc[m][n][r] * kScale;
    }
  }
}

// per-batch: s_j[b,i] = sum_j dots, s_all[b] = sum_ij dots (coalesced float4 + shfl)
__global__ __launch_bounds__(256) void reduce_k(
    const float* __restrict__ dots, float* __restrict__ s_j, float* __restrict__ s_all) {
  const int b = blockIdx.x, t = threadIdx.x, l = t & 63, w = t >> 6;
  const float4* dp = (const float4*)(dots + (long)b * Ss * Nn);
  __shared__ float rowacc[64][4];
  __shared__ float rowsum[64];
  for (int r = 0; r < 64; ++r) {
    const float4 v = dp[r * 256 + t];
    float s = v.x + v.y + v.z + v.w;
#pragma unroll
    for (int off = 32; off; off >>= 1) s += __shfl_down(s, off);
    if (l == 0) rowacc[r][w] = s;
  }
  __syncthreads();
  if (t < 64) {
    const float v = rowacc[t][0] + rowacc[t][1] + rowacc[t][2] + rowacc[t][3];
    rowsum[t] = v;
    s_j[b * 64 + t] = v;
  }
  __syncthreads();
  if (t < 64) {
    float v = rowsum[t];
#pragma unroll
    for (int off = 32; off; off >>= 1) v += __shfl_down(v, off);
    if (t == 0) s_all[b] = v;
  }
}

// attn = sigmoid(dots * s_all/s_j) -> out; inv_r = 1/(rowsum(attn)+eps)
__global__ __launch_bounds__(256) void attn_k(
    const float* __restrict__ dots, const float* __restrict__ s_j,
    const float* __restrict__ s_all, float* __restrict__ attn_out,
    float* __restrict__ inv_r) {
  const int bi = blockIdx.x;
  const int b = bi >> 6;
  const int t = threadIdx.x;
  const float ratio = s_all[b] / s_j[bi];
  const float* dp = dots + (long)bi * Nn;
  float* ap = attn_out + (long)bi * Nn;
  float s = 0.f;
#pragma unroll
  for (int qq = 0; qq < 4; qq++) {
    const int j = qq * 256 + t;
    const float x = dp[j] * ratio;
    const float a = 1.f / (1.f + expf(-x));
    ap[j] = a;
    s += a;
  }
  __shared__ float red[256];
  red[t] = s;
  __syncthreads();
  for (int off = 128; off > 0; off >>= 1) {
    if (t < off) red[t] += red[t + off];
    __syncthreads();
  }
  if (t == 0) inv_r[bi] = 1.f / (red[0] + kEps);
}

// updates[b,i,d] = inv_r[b,i] * sum_j attn[b,i,j] * inputs[b,j,d]  (fp32 reg tile)
// R15: j-tile 16 -> 20KB buffer, ring-3 = 60KB -> 2 blocks/CU (was 120KB -> 1).
// block = (b, dt in 0..1): 64 i x 256 d; thread tile 8i x 8d; pipeline = R11's
// race-proven order with per-tile vm-ops = 1 f4 + 4 gl_lds = 5 (vmcnt(5)->0).
__global__ __launch_bounds__(256) void updates_k5(
    const float* __restrict__ attn, const float* __restrict__ inputs,
    const float* __restrict__ inv_r, float* __restrict__ out0) {
  constexpr int NT2 = 64;      // 1024 / 16
  constexpr int BUF_F = 5120;  // floats per 20KB buffer: in@0 (4096), attT@4096 (1024)
  extern __shared__ float ldsf[];
  const int t = threadIdx.x, lam = t & 63, w = t >> 6;
  const int b = blockIdx.x >> 1, dt = blockIdx.x & 1;
  const int ig = t >> 5, dg = t & 31;
  const float* inb = inputs + (size_t)b * (Nn * Dd) + dt * 256;
  const float* attsrc = attn + (size_t)b * (Ss * Nn) + (size_t)(t >> 2) * Nn + (t & 3) * 4;
  float acc[8][8] = {};
  float4 ga, gb;

#define UISSUE(bufi, tile, G)                                             \
  {                                                                       \
    const int j0_ = (tile)*16;                                            \
    G = *(const float4*)(attsrc + j0_);                                   \
    float* db_ = ldsf + (bufi)*BUF_F;                                     \
    _Pragma("unroll") for (int i_ = 0; i_ < 4; i_++) {                    \
      const int row_ = i_ * 4 + w;                                        \
      gl_lds16(inb + (size_t)(j0_ + row_) * Dd + lam * 4, db_ + row_ * 256); \
    }                                                                     \
  }

#define UWRITE(bufi, G)                                                   \
  {                                                                       \
    float* ab_ = ldsf + (bufi)*BUF_F + 4096;                              \
    const int col_ = t >> 2;                                              \
    const int r0_ = (t & 3) * 4;                                          \
    ab_[(r0_ + 0) * 64 + col_] = G.x;                                     \
    ab_[(r0_ + 1) * 64 + col_] = G.y;                                     \
    ab_[(r0_ + 2) * 64 + col_] = G.z;                                     \
    ab_[(r0_ + 3) * 64 + col_] = G.w;                                     \
  }

#define UCOMP(bufi)                                                       \
  {                                                                       \
    const float* db_ = ldsf + (bufi)*BUF_F;                               \
    const float* ab_ = db_ + 4096;                                        \
    _Pragma("unroll 4") for (int jj = 0; jj < 16; jj++) {                 \
      float av[8], vv[8];                                                 \
      *(float4*)&av[0] = *(const float4*)(ab_ + jj * 64 + ig * 8);        \
      *(float4*)&av[4] = *(const float4*)(ab_ + jj * 64 + ig * 8 + 4);    \
      *(float4*)&vv[0] = *(const float4*)(db_ + jj * 256 + dg * 8);       \
      *(float4*)&vv[4] = *(const float4*)(db_ + jj * 256 + dg * 8 + 4);   \
      _Pragma("unroll") for (int m_ = 0; m_ < 8; m_++)                    \
          _Pragma("unroll") for (int n_ = 0; n_ < 8; n_++)                \
              acc[m_][n_] = __builtin_fmaf(av[m_], vv[n_], acc[m_][n_]);  \
    }                                                                     \
  }

  UISSUE(0, 0, ga);
  UISSUE(1, 1, gb);
  UWRITE(0, ga);

  for (int tt = 0; tt < NT2; tt += 2) {
    asm volatile("s_waitcnt vmcnt(5)" ::: "memory");
    UWRITE((tt + 1) % 3, gb);
    asm volatile("s_waitcnt lgkmcnt(0)" ::: "memory");
    __builtin_amdgcn_s_barrier();
    __builtin_amdgcn_sched_barrier(0);
    if (tt < NT2 - 2) UISSUE((tt + 2) % 3, tt + 2, ga);
    UCOMP(tt % 3);
    if (tt + 1 < NT2 - 1) {
      asm volatile("s_waitcnt vmcnt(5)" ::: "memory");
    } else {
      asm volatile("s_waitcnt vmcnt(0)" ::: "memory");
    }
    if (tt + 1 < NT2 - 1) UWRITE((tt + 2) % 3, ga);
    asm volatile("s_waitcnt lgkmcnt(0)" ::: "memory");
    __builtin_amdgcn_s_barrier();
    __builtin_amdgcn_sched_barrier(0);
    if (tt + 1 < NT2 - 2) UISSUE((tt + 3) % 3, tt + 3, gb);
    UCOMP((tt + 1) % 3);
  }
#undef UISSUE
#undef UWRITE
#undef UCOMP

#pragma unroll
  for (int m = 0; m < 8; m++) {
    const int i = ig * 8 + m;
    const float ir = inv_r[b * 64 + i];
    float4 o0, o1;
    o0.x = acc[m][0] * ir; o0.y = acc[m][1] * ir; o0.z = acc[m][2] * ir; o0.w = acc[m][3] * ir;
    o1.x = acc[m][4] * ir; o1.y = acc[m][5] * ir; o1.z = acc[m][6] * ir; o1.w = acc[m][7] * ir;
    float* op = out0 + (size_t)(b * 64 + i) * Dd + dt * 256 + dg * 8;
    *(float4*)op = o0;
    *(float4*)(op + 4) = o1;
  }
}

extern "C" void kernel_launch(void* const* d_in, const int* in_sizes, int n_in,
                              void* d_out, int out_size, void* d_ws, size_t ws_size,
                              hipStream_t stream) {
  (void)in_sizes; (void)n_in; (void)out_size; (void)ws_size;
  const float* inputs_pe = (const float*)d_in[0];
  const float* inputs = (const float*)d_in[1];
  const float* slots = (const float*)d_in[2];
  const float* W1 = (const float*)d_in[3];
  const float* b1 = (const float*)d_in[4];
  const float* W2 = (const float*)d_in[5];
  const float* b2 = (const float*)d_in[6];
  const float* W3 = (const float*)d_in[7];
  const float* b3 = (const float*)d_in[8];

  char* ws = (char*)d_ws;
  size_t off = 0;
  auto alloc = [&](size_t bytes) -> void* {
    void* p = ws + off;
    off += (bytes + 255) & ~(size_t)255;
    return p;
  };
  const size_t actB = (size_t)Bb * Nn * 1024 * 2;  // interleaved split activation
  unsigned short* AI = (unsigned short*)alloc(actB);
  unsigned short* BI = (unsigned short*)alloc(actB);
  unsigned short* w1i = (unsigned short*)alloc(Dd * 1024 * 2);
  unsigned short* w2i = (unsigned short*)alloc(Dd * 1024 * 2);
  unsigned short* w3i = (unsigned short*)alloc(Dd * 1024 * 2);
  unsigned short* qi = (unsigned short*)alloc(Ss * 1024 * 2);
  float* dotsb = (float*)alloc((size_t)Bb * Ss * Nn * 4);
  float* s_j = (float*)alloc(Bb * Ss * 4);
  float* s_all = (float*)alloc(Bb * 4);
  float* inv_r = (float*)alloc(Bb * Ss * 4);

  float* out_updates = (float*)d_out;
  float* out_attn = out_updates + (size_t)Bb * Ss * Dd;

  const int kLdsG = 4 * 16 * 1024;  // 64KB ring-4 -> 2 blocks/CU
  const int kLdsU = 3 * 20 * 1024;  // 60KB ring-3 -> 2 blocks/CU
  hipFuncSetAttribute(reinterpret_cast<const void*>(gemm_2b<1>),
                      hipFuncAttributeMaxDynamicSharedMemorySize, kLdsG);
  hipFuncSetAttribute(reinterpret_cast<const void*>(gemm_2b<0>),
                      hipFuncAttributeMaxDynamicSharedMemorySize, kLdsG);
  hipFuncSetAttribute(reinterpret_cast<const void*>(updates_k5),
                      hipFuncAttributeMaxDynamicSharedMemorySize, kLdsU);

  cast_split_i<<<4096, 256, 0, stream>>>(inputs_pe, AI, Bb * Nn * Dd / 8);
  cast_split_i<<<128, 256, 0, stream>>>(W1, w1i, Dd * Dd / 8);
  cast_split_i<<<128, 256, 0, stream>>>(W2, w2i, Dd * Dd / 8);
  cast_split_i<<<128, 256, 0, stream>>>(W3, w3i, Dd * Dd / 8);
  cast_split_i<<<16, 256, 0, stream>>>(slots, qi, Ss * Dd / 8);

  gemm_2b<1><<<4096, 512, kLdsG, stream>>>(AI, w1i, b1, BI);
  gemm_2b<1><<<4096, 512, kLdsG, stream>>>(BI, w2i, b2, AI);
  gemm_2b<0><<<4096, 512, kLdsG, stream>>>(AI, w3i, b3, BI);

  gemm_dots_split<<<Bb * 8, 256, 0, stream>>>(qi, BI, dotsb);
  reduce_k<<<Bb, 256, 0, stream>>>(dotsb, s_j, s_all);
  attn_k<<<Bb * Ss, 256, 0, stream>>>(dotsb, s_j, s_all, out_attn, inv_r);
  updates_k5<<<Bb * 2, 256, kLdsU, stream>>>(out_attn, inputs, inv_r, out_updates);
}

// Round 16
// 1053.703 us; speedup vs baseline: 1.1778x; 1.1236x over previous
//
#include <hip/hip_runtime.h>
#include <stdint.h>

#define Bb 128
#define Nn 1024
#define Dd 512
#define Ss 64

constexpr float kScale = 0.044194173824159216f;  // 512^-0.5
constexpr float kEps = 1e-8f;

typedef __bf16 bf16x8 __attribute__((ext_vector_type(8)));
typedef float f32x4 __attribute__((ext_vector_type(4)));
typedef float f32x16 __attribute__((ext_vector_type(16)));
typedef unsigned short ushort8 __attribute__((ext_vector_type(8)));

#define MFMA32 __builtin_amdgcn_mfma_f32_32x32x16_bf16

__device__ inline unsigned short f2bf_rne(float x) {
  unsigned u = __builtin_bit_cast(unsigned, x);
  u += 0x7FFFu + ((u >> 16) & 1u);
  return (unsigned short)(u >> 16);
}
__device__ inline float bf2f(unsigned short h) {
  unsigned u = ((unsigned)h) << 16;
  return __builtin_bit_cast(float, u);
}

// async global->LDS, 16B per lane; LDS dest must be wave-uniform base (HW adds lane*16)
__device__ inline void gl_lds16(const void* g, void* l) {
  typedef unsigned int u32;
  auto gp = (u32 __attribute__((address_space(1)))*)(unsigned long long)(uintptr_t)g;
  auto lp = (u32 __attribute__((address_space(3)))*)(unsigned int)(uintptr_t)l;
  __builtin_amdgcn_global_load_lds(gp, lp, 16, 0, 0);
}

// f32 -> INTERLEAVED split bf16: out[granule*16 + 0..7] = hi, [+8..15] = lo.
__global__ void cast_split_i(const float* __restrict__ in,
                             unsigned short* __restrict__ out, int n8) {
  int i = blockIdx.x * blockDim.x + threadIdx.x;
  const int stride = gridDim.x * blockDim.x;
  for (; i < n8; i += stride) {
    const float4 v0 = ((const float4*)in)[i * 2];
    const float4 v1 = ((const float4*)in)[i * 2 + 1];
    float f[8] = {v0.x, v0.y, v0.z, v0.w, v1.x, v1.y, v1.z, v1.w};
    ushort8 h, lo;
#pragma unroll
    for (int j = 0; j < 8; j++) {
      h[j] = f2bf_rne(f[j]);
      lo[j] = f2bf_rne(f[j] - bf2f(h[j]));
    }
    ((ushort8*)out)[i * 2] = h;
    ((ushort8*)out)[i * 2 + 1] = lo;
  }
}

// C[M,512] = act(A[M,512] @ W[512,512]^T + bias), FUSED 3-term split bf16.
// Interleaved split layout [row][1024 ushorts], granule g at g*16 (+0 hi, +8 lo).
// R16: R11 geometry/staging/swizzle VERBATIM (BM=BN=256, 8 waves 2Mx4N,
// wave-tile 128x64, K-half 16, ring-4 x 32KB, m97-granularity staging), but the
// per-half body is the m201 FINE PHASE INTERLEAVE:
//   gate: vmcnt(8|4|0) BEFORE s_barrier (race-proven order); STG(h+3) after;
//   P0 {read A01+B0 (6xb128); barrier; lgkm(0); setprio 6 MFMA}
//   P1 {read A23        (4); barrier; lgkm(0); 6 MFMA}
//   P2 {read B1         (2); barrier; lgkm(0); 6 MFMA}
//   P3 {                     barrier;          6 MFMA}
// Reads issue before each phase barrier -> drain under sibling waves' MFMA;
// vmcnt never drains to 0 in-loop (T4); per-phase role split enables T5.
template <int ACT>
__global__ __launch_bounds__(512, 1) void gemm_8p(
    const unsigned short* __restrict__ A, const unsigned short* __restrict__ W,
    const float* __restrict__ bias, unsigned short* __restrict__ C) {
  constexpr int NH = 32;  // K=512 / 16
  extern __shared__ unsigned short lds[];  // 4 x 16384 ushorts = 128KB
  const int t = threadIdx.x, l = t & 63, w = t >> 6;
  const int wr = w >> 2, wc = w & 3;

  // bijective XCD-chunked swizzle (1024 = 8 x 128); wg pairs share the A panel
  const int wg = ((blockIdx.x & 7) << 7) + (blockIdx.x >> 3);
  const long rowA0 = (long)(wg >> 1) * 256;
  const int colB0 = (wg & 1) * 256;

  // ---- staging (R11 verbatim): 32 chunks/slot (16 rows x 64B); 4 per wave ----
  const unsigned short* base8 = (w < 4) ? A + rowA0 * 1024 : W + (long)colB0 * 1024;
  const int p2s = ((l >> 1) ^ (l >> 4)) & 1;
  const unsigned short* srcp[4];
  int dstp[4];
#pragma unroll
  for (int j = 0; j < 4; j++) {
    const int cid = (w & 3) * 4 + j;
    srcp[j] = base8 + (long)(cid * 16 + (l >> 2)) * 1024 + p2s * 16 + (l & 1) * 8;
    dstp[j] = (w * 4 + j) * 512;  // + lane*8 implicit
  }
#define STG(h)                                                            \
  {                                                                       \
    unsigned short* bq_ = lds + ((h) & 3) * 16384;                        \
    _Pragma("unroll") for (int j = 0; j < 4; j++)                         \
        gl_lds16(srcp[j] + (h) * 32, bq_ + dstp[j]);                      \
  }

  // ---- frag reads (R11 verbatim): stored pair pos = (l>>5)^((l>>2)&1) ----
  const int pp16 = (((l >> 5) ^ ((l >> 2) & 1))) * 16;
  const int abase0 = (wr * 128 + (l & 31)) * 32 + pp16;          // A @0
  const int bbase0 = 8192 + (wc * 64 + (l & 31)) * 32 + pp16;    // W @8192

  f32x16 acc[4][2] = {};
  bf16x8 ah[4], al[4], bh0, bl0, bh1, bl1;

#define PH_BAR()                                                          \
  __builtin_amdgcn_s_barrier();                                           \
  asm volatile("s_waitcnt lgkmcnt(0)" ::: "memory");                      \
  __builtin_amdgcn_sched_barrier(0);

#define MFMA6(MA, MB, BH, BL)                                             \
  __builtin_amdgcn_s_setprio(1);                                          \
  acc[MA][( &BH == &bh0 ) ? 0 : 1] = acc[MA][(&BH == &bh0) ? 0 : 1];      \
  __builtin_amdgcn_s_setprio(0);

  // (MFMA6 placeholder unused; explicit clusters below)

  STG(0); STG(1); STG(2);

  for (int h = 0; h < NH; ++h) {
    // ---- gate (race-proven order: vmcnt BEFORE barrier) ----
    if (h < NH - 2) {
      asm volatile("s_waitcnt vmcnt(8)" ::: "memory");
    } else if (h == NH - 2) {
      asm volatile("s_waitcnt vmcnt(4)" ::: "memory");
    } else {
      asm volatile("s_waitcnt vmcnt(0)" ::: "memory");
    }
    __builtin_amdgcn_s_barrier();
    __builtin_amdgcn_sched_barrier(0);
    if (h + 3 < NH) STG(h + 3);
    const unsigned short* bq = lds + (h & 3) * 16384;

    // ---- P0: read A01 + B0, then MFMA (m=0,1; n=0) ----
    ah[0] = *(const bf16x8*)(bq + abase0);
    al[0] = *(const bf16x8*)(bq + abase0 + 8);
    ah[1] = *(const bf16x8*)(bq + abase0 + 1024);
    al[1] = *(const bf16x8*)(bq + abase0 + 1024 + 8);
    bh0 = *(const bf16x8*)(bq + bbase0);
    bl0 = *(const bf16x8*)(bq + bbase0 + 8);
    PH_BAR()
    __builtin_amdgcn_s_setprio(1);
    acc[0][0] = MFMA32(ah[0], bh0, acc[0][0], 0, 0, 0);
    acc[0][0] = MFMA32(al[0], bh0, acc[0][0], 0, 0, 0);
    acc[0][0] = MFMA32(ah[0], bl0, acc[0][0], 0, 0, 0);
    acc[1][0] = MFMA32(ah[1], bh0, acc[1][0], 0, 0, 0);
    acc[1][0] = MFMA32(al[1], bh0, acc[1][0], 0, 0, 0);
    acc[1][0] = MFMA32(ah[1], bl0, acc[1][0], 0, 0, 0);
    __builtin_amdgcn_s_setprio(0);
    __builtin_amdgcn_sched_barrier(0);

    // ---- P1: read A23, then MFMA (m=2,3; n=0) ----
    ah[2] = *(const bf16x8*)(bq + abase0 + 2048);
    al[2] = *(const bf16x8*)(bq + abase0 + 2048 + 8);
    ah[3] = *(const bf16x8*)(bq + abase0 + 3072);
    al[3] = *(const bf16x8*)(bq + abase0 + 3072 + 8);
    PH_BAR()
    __builtin_amdgcn_s_setprio(1);
    acc[2][0] = MFMA32(ah[2], bh0, acc[2][0], 0, 0, 0);
    acc[2][0] = MFMA32(al[2], bh0, acc[2][0], 0, 0, 0);
    acc[2][0] = MFMA32(ah[2], bl0, acc[2][0], 0, 0, 0);
    acc[3][0] = MFMA32(ah[3], bh0, acc[3][0], 0, 0, 0);
    acc[3][0] = MFMA32(al[3], bh0, acc[3][0], 0, 0, 0);
    acc[3][0] = MFMA32(ah[3], bl0, acc[3][0], 0, 0, 0);
    __builtin_amdgcn_s_setprio(0);
    __builtin_amdgcn_sched_barrier(0);

    // ---- P2: read B1, then MFMA (m=0,1; n=1) ----
    bh1 = *(const bf16x8*)(bq + bbase0 + 1024);
    bl1 = *(const bf16x8*)(bq + bbase0 + 1024 + 8);
    PH_BAR()
    __builtin_amdgcn_s_setprio(1);
    acc[0][1] = MFMA32(ah[0], bh1, acc[0][1], 0, 0, 0);
    acc[0][1] = MFMA32(al[0], bh1, acc[0][1], 0, 0, 0);
    acc[0][1] = MFMA32(ah[0], bl1, acc[0][1], 0, 0, 0);
    acc[1][1] = MFMA32(ah[1], bh1, acc[1][1], 0, 0, 0);
    acc[1][1] = MFMA32(al[1], bh1, acc[1][1], 0, 0, 0);
    acc[1][1] = MFMA32(ah[1], bl1, acc[1][1], 0, 0, 0);
    __builtin_amdgcn_s_setprio(0);
    __builtin_amdgcn_sched_barrier(0);

    // ---- P3: MFMA (m=2,3; n=1) ----
    __builtin_amdgcn_s_barrier();
    __builtin_amdgcn_sched_barrier(0);
    __builtin_amdgcn_s_setprio(1);
    acc[2][1] = MFMA32(ah[2], bh1, acc[2][1], 0, 0, 0);
    acc[2][1] = MFMA32(al[2], bh1, acc[2][1], 0, 0, 0);
    acc[2][1] = MFMA32(ah[2], bl1, acc[2][1], 0, 0, 0);
    acc[3][1] = MFMA32(ah[3], bh1, acc[3][1], 0, 0, 0);
    acc[3][1] = MFMA32(al[3], bh1, acc[3][1], 0, 0, 0);
    acc[3][1] = MFMA32(ah[3], bl1, acc[3][1], 0, 0, 0);
    __builtin_amdgcn_s_setprio(0);
    __builtin_amdgcn_sched_barrier(0);
  }
#undef STG
#undef PH_BAR
#undef MFMA6

  // epilogue (R11 verbatim): C/D 32x32: col = l&31, row = (r&3)+8*(r>>2)+4*(l>>5);
  // interleaved write: hi at row*1024 + (col>>3)*16 + (col&7), lo at +8.
#pragma unroll
  for (int m = 0; m < 4; m++)
#pragma unroll
    for (int n = 0; n < 2; n++) {
      const int col = colB0 + wc * 64 + n * 32 + (l & 31);
      const float bv = bias[col];
      const int cofs = (col >> 3) * 16 + (col & 7);
#pragma unroll
      for (int r = 0; r < 16; r++) {
        const long row = rowA0 + wr * 128 + m * 32 + (r & 3) + 8 * (r >> 2) + 4 * (l >> 5);
        float xv = acc[m][n][r] + bv;
        if (ACT) xv = fmaxf(xv, 0.0f);
        const unsigned short h = f2bf_rne(xv);
        unsigned short* cp = C + row * 1024 + cofs;
        cp[0] = h;
        cp[8] = f2bf_rne(xv - bf2f(h));
      }
    }
}

// dots[b,64,1024] = scale * slots[64,512] @ k[b,1024,512]^T  (interleaved split in)
__global__ __launch_bounds__(256) void gemm_dots_split(
    const unsigned short* __restrict__ QI, const unsigned short* __restrict__ KI,
    float* __restrict__ dots) {
  constexpr int K = 512, BM = 64, BN = 128, BK = 32;
  __shared__ __align__(16) unsigned short lah[BM * BK];
  __shared__ __align__(16) unsigned short lal[BM * BK];
  __shared__ __align__(16) unsigned short lbh[BN * BK];
  __shared__ __align__(16) unsigned short lbl[BN * BK];
  const int t = threadIdx.x, l = t & 63, w = t >> 6;
  const int b = blockIdx.x >> 3, bc = blockIdx.x & 7;
  const unsigned short* kb = KI + (long)b * Nn * 1024;
  f32x4 acc[4][2] = {};

  const int qbase = (t >> 2) * 1024 + (t & 3) * 16;
  const long kbase0 = (long)(bc * BN + (t >> 2)) * 1024 + (t & 3) * 16;
  const long kbase1 = (long)(bc * BN + 64 + (t >> 2)) * 1024 + (t & 3) * 16;

  for (int k0 = 0; k0 < K; k0 += BK) {
    const int ko = k0 * 2;  // ushort offset of granule (k0>>3)*16
    const int lo = w * 512;
    gl_lds16(QI + qbase + ko, lah + lo);
    gl_lds16(QI + qbase + ko + 8, lal + lo);
    gl_lds16(kb + kbase0 + ko, lbh + lo);
    gl_lds16(kb + kbase0 + ko + 8, lbl + lo);
    gl_lds16(kb + kbase1 + ko, lbh + 2048 + lo);
    gl_lds16(kb + kbase1 + ko + 8, lbl + 2048 + lo);
    __syncthreads();
    bf16x8 ah[4], al[4], bh[2], bl[2];
#pragma unroll
    for (int m = 0; m < 4; m++) {
      const int off = (m * 16 + (l & 15)) * BK + (l >> 4) * 8;
      ah[m] = *(const bf16x8*)(lah + off);
      al[m] = *(const bf16x8*)(lal + off);
    }
#pragma unroll
    for (int n = 0; n < 2; n++) {
      const int off = (w * 32 + n * 16 + (l & 15)) * BK + (l >> 4) * 8;
      bh[n] = *(const bf16x8*)(lbh + off);
      bl[n] = *(const bf16x8*)(lbl + off);
    }
#pragma unroll
    for (int m = 0; m < 4; m++)
#pragma unroll
      for (int n = 0; n < 2; n++) {
        acc[m][n] = __builtin_amdgcn_mfma_f32_16x16x32_bf16(ah[m], bh[n], acc[m][n], 0, 0, 0);
        acc[m][n] = __builtin_amdgcn_mfma_f32_16x16x32_bf16(al[m], bh[n], acc[m][n], 0, 0, 0);
        acc[m][n] = __builtin_amdgcn_mfma_f32_16x16x32_bf16(ah[m], bl[n], acc[m][n], 0, 0, 0);
      }
    __syncthreads();
  }
  float* dp = dots + (long)b * Ss * Nn;
#pragma unroll
  for (int m = 0; m < 4; m++) {
    const int row = m * 16 + (l >> 4) * 4;
#pragma unroll
    for (int n = 0; n < 2; n++) {
      const int col = bc * BN + w * 32 + n * 16 + (l & 15);
#pragma unroll
      for (int r = 0; r < 4; r++) dp[(long)(row + r) * Nn + col] = acc[m][n][r] * kScale;
    }
  }
}

// per-batch: s_j[b,i] = sum_j dots, s_all[b] = sum_ij dots (coalesced float4 + shfl)
__global__ __launch_bounds__(256) void reduce_k(
    const float* __restrict__ dots, float* __restrict__ s_j, float* __restrict__ s_all) {
  const int b = blockIdx.x, t = threadIdx.x, l = t & 63, w = t >> 6;
  const float4* dp = (const float4*)(dots + (long)b * Ss * Nn);
  __shared__ float rowacc[64][4];
  __shared__ float rowsum[64];
  for (int r = 0; r < 64; ++r) {
    const float4 v = dp[r * 256 + t];
    float s = v.x + v.y + v.z + v.w;
#pragma unroll
    for (int off = 32; off; off >>= 1) s += __shfl_down(s, off);
    if (l == 0) rowacc[r][w] = s;
  }
  __syncthreads();
  if (t < 64) {
    const float v = rowacc[t][0] + rowacc[t][1] + rowacc[t][2] + rowacc[t][3];
    rowsum[t] = v;
    s_j[b * 64 + t] = v;
  }
  __syncthreads();
  if (t < 64) {
    float v = rowsum[t];
#pragma unroll
    for (int off = 32; off; off >>= 1) v += __shfl_down(v, off);
    if (t == 0) s_all[b] = v;
  }
}

// attn = sigmoid(dots * s_all/s_j) -> out; inv_r = 1/(rowsum(attn)+eps)
__global__ __launch_bounds__(256) void attn_k(
    const float* __restrict__ dots, const float* __restrict__ s_j,
    const float* __restrict__ s_all, float* __restrict__ attn_out,
    float* __restrict__ inv_r) {
  const int bi = blockIdx.x;
  const int b = bi >> 6;
  const int t = threadIdx.x;
  const float ratio = s_all[b] / s_j[bi];
  const float* dp = dots + (long)bi * Nn;
  float* ap = attn_out + (long)bi * Nn;
  float s = 0.f;
#pragma unroll
  for (int qq = 0; qq < 4; qq++) {
    const int j = qq * 256 + t;
    const float x = dp[j] * ratio;
    const float a = 1.f / (1.f + expf(-x));
    ap[j] = a;
    s += a;
  }
  __shared__ float red[256];
  red[t] = s;
  __syncthreads();
  for (int off = 128; off > 0; off >>= 1) {
    if (t < off) red[t] += red[t + off];
    __syncthreads();
  }
  if (t == 0) inv_r[bi] = 1.f / (red[0] + kEps);
}

// updates[b,i,d] = inv_r[b,i] * sum_j attn[b,i,j] * inputs[b,j,d]  (fp32 register tile)
__global__ __launch_bounds__(256, 1) void updates_k2(
    const float* __restrict__ attn, const float* __restrict__ inputs,
    const float* __restrict__ inv_r, float* __restrict__ out0) {
  constexpr int NT2 = 32;
  constexpr int BUF_F = 10240;
  extern __shared__ float ldsf[];
  const int t = threadIdx.x, lam = t & 63, w = t >> 6;
  const int b = blockIdx.x >> 1, dt = blockIdx.x & 1;
  const int ig = t >> 5, dg = t & 31;
  const float* inb = inputs + (size_t)b * (Nn * Dd) + dt * 256;
  const float* attsrc = attn + (size_t)b * (Ss * Nn) + (size_t)(t >> 2) * Nn + (t & 3) * 8;
  float acc[8][8] = {};
  float4 ga0, ga1, gb0, gb1;

#define UISSUE(bufi, tile, G0, G1)                                        \
  {                                                                       \
    const int j0_ = (tile)*32;                                            \
    G0 = *(const float4*)(attsrc + j0_);                                  \
    G1 = *(const float4*)(attsrc + j0_ + 4);                              \
    float* db_ = ldsf + (bufi)*BUF_F;                                     \
    _Pragma("unroll") for (int i_ = 0; i_ < 8; i_++) {                    \
      const int row_ = i_ * 4 + w;                                        \
      gl_lds16(inb + (size_t)(j0_ + row_) * Dd + lam * 4, db_ + row_ * 256); \
    }                                                                     \
  }

#define UWRITE(bufi, G0, G1)                                              \
  {                                                                       \
    float* ab_ = ldsf + (bufi)*BUF_F + 8192;                              \
    const int col_ = t >> 2;                                              \
    const int r0_ = (t & 3) * 8;                                          \
    ab_[(r0_ + 0) * 64 + col_] = G0.x;                                    \
    ab_[(r0_ + 1) * 64 + col_] = G0.y;                                    \
    ab_[(r0_ + 2) * 64 + col_] = G0.z;                                    \
    ab_[(r0_ + 3) * 64 + col_] = G0.w;                                    \
    ab_[(r0_ + 4) * 64 + col_] = G1.x;                                    \
    ab_[(r0_ + 5) * 64 + col_] = G1.y;                                    \
    ab_[(r0_ + 6) * 64 + col_] = G1.z;                                    \
    ab_[(r0_ + 7) * 64 + col_] = G1.w;                                    \
  }

#define UCOMP(bufi)                                                       \
  {                                                                       \
    const float* db_ = ldsf + (bufi)*BUF_F;                               \
    const float* ab_ = db_ + 8192;                                        \
    _Pragma("unroll 4") for (int jj = 0; jj < 32; jj++) {                 \
      float av[8], vv[8];                                                 \
      *(float4*)&av[0] = *(const float4*)(ab_ + jj * 64 + ig * 8);        \
      *(float4*)&av[4] = *(const float4*)(ab_ + jj * 64 + ig * 8 + 4);    \
      *(float4*)&vv[0] = *(const float4*)(db_ + jj * 256 + dg * 8);       \
      *(float4*)&vv[4] = *(const float4*)(db_ + jj * 256 + dg * 8 + 4);   \
      _Pragma("unroll") for (int m_ = 0; m_ < 8; m_++)                    \
          _Pragma("unroll") for (int n_ = 0; n_ < 8; n_++)                \
              acc[m_][n_] = __builtin_fmaf(av[m_], vv[n_], acc[m_][n_]);  \
    }                                                                     \
  }

  UISSUE(0, 0, ga0, ga1);
  UISSUE(1, 1, gb0, gb1);
  UWRITE(0, ga0, ga1);

  for (int tt = 0; tt < NT2; tt += 2) {
    asm volatile("s_waitcnt vmcnt(10)" ::: "memory");
    UWRITE((tt + 1) % 3, gb0, gb1);
    asm volatile("s_waitcnt lgkmcnt(0)" ::: "memory");
    __builtin_amdgcn_s_barrier();
    __builtin_amdgcn_sched_barrier(0);
    if (tt < NT2 - 2) UISSUE((tt + 2) % 3, tt + 2, ga0, ga1);
    UCOMP(tt % 3);
    if (tt + 1 < NT2 - 1) {
      asm volatile("s_waitcnt vmcnt(10)" ::: "memory");
    } else {
      asm volatile("s_waitcnt vmcnt(0)" ::: "memory");
    }
    if (tt + 1 < NT2 - 1) UWRITE((tt + 2) % 3, ga0, ga1);
    asm volatile("s_waitcnt lgkmcnt(0)" ::: "memory");
    __builtin_amdgcn_s_barrier();
    __builtin_amdgcn_sched_barrier(0);
    if (tt + 1 < NT2 - 2) UISSUE((tt + 3) % 3, tt + 3, gb0, gb1);
    UCOMP((tt + 1) % 3);
  }
#undef UISSUE
#undef UWRITE
#undef UCOMP

#pragma unroll
  for (int m = 0; m < 8; m++) {
    const int i = ig * 8 + m;
    const float ir = inv_r[b * 64 + i];
    float4 o0, o1;
    o0.x = acc[m][0] * ir; o0.y = acc[m][1] * ir; o0.z = acc[m][2] * ir; o0.w = acc[m][3] * ir;
    o1.x = acc[m][4] * ir; o1.y = acc[m][5] * ir; o1.z = acc[m][6] * ir; o1.w = acc[m][7] * ir;
    float* op = out0 + (size_t)(b * 64 + i) * Dd + dt * 256 + dg * 8;
    *(float4*)op = o0;
    *(float4*)(op + 4) = o1;
  }
}

extern "C" void kernel_launch(void* const* d_in, const int* in_sizes, int n_in,
                              void* d_out, int out_size, void* d_ws, size_t ws_size,
                              hipStream_t stream) {
  (void)in_sizes; (void)n_in; (void)out_size; (void)ws_size;
  const float* inputs_pe = (const float*)d_in[0];
  const float* inputs = (const float*)d_in[1];
  const float* slots = (const float*)d_in[2];
  const float* W1 = (const float*)d_in[3];
  const float* b1 = (const float*)d_in[4];
  const float* W2 = (const float*)d_in[5];
  const float* b2 = (const float*)d_in[6];
  const float* W3 = (const float*)d_in[7];
  const float* b3 = (const float*)d_in[8];

  char* ws = (char*)d_ws;
  size_t off = 0;
  auto alloc = [&](size_t bytes) -> void* {
    void* p = ws + off;
    off += (bytes + 255) & ~(size_t)255;
    return p;
  };
  const size_t actB = (size_t)Bb * Nn * 1024 * 2;  // interleaved split activation
  unsigned short* AI = (unsigned short*)alloc(actB);
  unsigned short* BI = (unsigned short*)alloc(actB);
  unsigned short* w1i = (unsigned short*)alloc(Dd * 1024 * 2);
  unsigned short* w2i = (unsigned short*)alloc(Dd * 1024 * 2);
  unsigned short* w3i = (unsigned short*)alloc(Dd * 1024 * 2);
  unsigned short* qi = (unsigned short*)alloc(Ss * 1024 * 2);
  float* dotsb = (float*)alloc((size_t)Bb * Ss * Nn * 4);
  float* s_j = (float*)alloc(Bb * Ss * 4);
  float* s_all = (float*)alloc(Bb * 4);
  float* inv_r = (float*)alloc(Bb * Ss * 4);

  float* out_updates = (float*)d_out;
  float* out_attn = out_updates + (size_t)Bb * Ss * Dd;

  const int kLdsG = 4 * 32 * 1024;  // 128KB ring-4
  const int kLdsU = 3 * 40 * 1024;  // 120KB for updates_k2
  hipFuncSetAttribute(reinterpret_cast<const void*>(gemm_8p<1>),
                      hipFuncAttributeMaxDynamicSharedMemorySize, kLdsG);
  hipFuncSetAttribute(reinterpret_cast<const void*>(gemm_8p<0>),
                      hipFuncAttributeMaxDynamicSharedMemorySize, kLdsG);
  hipFuncSetAttribute(reinterpret_cast<const void*>(updates_k2),
                      hipFuncAttributeMaxDynamicSharedMemorySize, kLdsU);

  cast_split_i<<<4096, 256, 0, stream>>>(inputs_pe, AI, Bb * Nn * Dd / 8);
  cast_split_i<<<128, 256, 0, stream>>>(W1, w1i, Dd * Dd / 8);
  cast_split_i<<<128, 256, 0, stream>>>(W2, w2i, Dd * Dd / 8);
  cast_split_i<<<128, 256, 0, stream>>>(W3, w3i, Dd * Dd / 8);
  cast_split_i<<<16, 256, 0, stream>>>(slots, qi, Ss * Dd / 8);

  gemm_8p<1><<<1024, 512, kLdsG, stream>>>(AI, w1i, b1, BI);
  gemm_8p<1><<<1024, 512, kLdsG, stream>>>(BI, w2i, b2, AI);
  gemm_8p<0><<<1024, 512, kLdsG, stream>>>(AI, w3i, b3, BI);

  gemm_dots_split<<<Bb * 8, 256, 0, stream>>>(qi, BI, dotsb);
  reduce_k<<<Bb, 256, 0, stream>>>(dotsb, s_j, s_all);
  attn_k<<<Bb * Ss, 256, 0, stream>>>(dotsb, s_j, s_all, out_attn, inv_r);
  updates_k2<<<Bb * 2, 256, kLdsU, stream>>>(out_attn, inputs, inv_r, out_updates);
}

// Round 17
// 1039.886 us; speedup vs baseline: 1.1935x; 1.0133x over previous
//
#include <hip/hip_runtime.h>
#include <stdint.h>

#define Bb 128
#define Nn 1024
#define Dd 512
#define Ss 64

constexpr float kScale = 0.044194173824159216f;  // 512^-0.5
constexpr float kEps = 1e-8f;

typedef __bf16 bf16x8 __attribute__((ext_vector_type(8)));
typedef float f32x4 __attribute__((ext_vector_type(4)));
typedef float f32x16 __attribute__((ext_vector_type(16)));
typedef unsigned short ushort8 __attribute__((ext_vector_type(8)));

#define MFMA32 __builtin_amdgcn_mfma_f32_32x32x16_bf16

__device__ inline unsigned short f2bf_rne(float x) {
  unsigned u = __builtin_bit_cast(unsigned, x);
  u += 0x7FFFu + ((u >> 16) & 1u);
  return (unsigned short)(u >> 16);
}
__device__ inline float bf2f(unsigned short h) {
  unsigned u = ((unsigned)h) << 16;
  return __builtin_bit_cast(float, u);
}

// async global->LDS, 16B per lane; LDS dest must be wave-uniform base (HW adds lane*16)
__device__ inline void gl_lds16(const void* g, void* l) {
  typedef unsigned int u32;
  auto gp = (u32 __attribute__((address_space(1)))*)(unsigned long long)(uintptr_t)g;
  auto lp = (u32 __attribute__((address_space(3)))*)(unsigned int)(uintptr_t)l;
  __builtin_amdgcn_global_load_lds(gp, lp, 16, 0, 0);
}

// f32 -> INTERLEAVED split bf16: out[granule*16 + 0..7] = hi, [+8..15] = lo.
__global__ void cast_split_i(const float* __restrict__ in,
                             unsigned short* __restrict__ out, int n8) {
  int i = blockIdx.x * blockDim.x + threadIdx.x;
  const int stride = gridDim.x * blockDim.x;
  for (; i < n8; i += stride) {
    const float4 v0 = ((const float4*)in)[i * 2];
    const float4 v1 = ((const float4*)in)[i * 2 + 1];
    float f[8] = {v0.x, v0.y, v0.z, v0.w, v1.x, v1.y, v1.z, v1.w};
    ushort8 h, lo;
#pragma unroll
    for (int j = 0; j < 8; j++) {
      h[j] = f2bf_rne(f[j]);
      lo[j] = f2bf_rne(f[j] - bf2f(h[j]));
    }
    ((ushort8*)out)[i * 2] = h;
    ((ushort8*)out)[i * 2 + 1] = lo;
  }
}

// C[M,512] = act(A[M,512] @ W[512,512]^T + bias), FUSED 3-term split bf16.
// Interleaved split layout [row][1024 ushorts], granule g at g*16 (+0 hi, +8 lo).
// R17: gate amortization. BM=BN=256, 8 waves (2Mx4N), wave-tile 128x64,
// 32x32x16 MFMA. K-STEP = 32 (was 16): ring-2 x 64KB slots (A[256][64u] @0,
// W[256][64u] @16384u; rows are 128B), 16 gates (was 32), 7 phases x 6-12 MFMA
// per gate (48 MFMA/gate). STG(s+1) issued at TOP of step s -> a full step
// (~3000cyc >> 900 HBM) of landing slack -> gate vmcnt(0) is a free drain.
// Race-audit: all waves' step-(s-1) ds_reads are lgkm-drained before they cross
// gate(s); STG(s+1) (same ring slot) issues only after that barrier.
// Swizzle (128B rows wrap all banks): stored piece p' = p ^ (row&7) -> every
// 8-lane frag group hits all 8 bank-quads; staging source qs = (l&7)^((l>>3)&7)
// (involution), linear LDS dest. kk=1 offset = kk=0 ^32 (ushorts); lo = ^8.
// Phase schedule (reads | MFMA): P0 A01k0+B0k0|m01n0k0, P1 A23k0|m23n0k0,
// P2 B1k0|m01n1k0, P3 A01k1+B0k1|m23n1k0, P4 A23k1|m01n0k1, P5 B1k1|m23n0k1,
// P6 -|m01n1k1+m23n1k1. Register-overwrite deps audited clean.
template <int ACT>
__global__ __launch_bounds__(512, 1) void gemm_g2(
    const unsigned short* __restrict__ A, const unsigned short* __restrict__ W,
    const float* __restrict__ bias, unsigned short* __restrict__ C) {
  constexpr int NS = 16;  // K=512 / 32
  extern __shared__ unsigned short lds[];  // 2 x 32768 ushorts = 128KB
  const int t = threadIdx.x, l = t & 63, w = t >> 6;
  const int wr = w >> 2, wc = w & 3;

  // bijective XCD-chunked swizzle (1024 = 8 x 128); wg pairs share the A panel
  const int wg = ((blockIdx.x & 7) << 7) + (blockIdx.x >> 3);
  const long rowA0 = (long)(wg >> 1) * 256;
  const int colB0 = (wg & 1) * 256;

  // ---- staging: 64 chunks/slot (8 rows x 128B each); 8 per wave ----
  // w<4 -> A local chunks (w&3)*8+j ; w>=4 -> W. lane l: row = cl*8 + (l>>3),
  // dest piece l&7 (linear), source piece qs = (l&7) ^ ((l>>3)&7).
  const unsigned short* base8 = (w < 4) ? A + rowA0 * 1024 : W + (long)colB0 * 1024;
  const int qs = (l & 7) ^ ((l >> 3) & 7);
  const unsigned short* srcp[8];
  int dstp[8];
#pragma unroll
  for (int j = 0; j < 8; j++) {
    const int cl = (w & 3) * 8 + j;  // local chunk 0..31
    const int row = cl * 8 + (l >> 3);
    srcp[j] = base8 + (long)row * 1024 + qs * 8;
    dstp[j] = (w < 4 ? 0 : 16384) + cl * 512;  // + lane*8 implicit
  }
#define STG(s)                                                            \
  {                                                                       \
    unsigned short* bq_ = lds + ((s) & 1) * 32768;                        \
    _Pragma("unroll") for (int j = 0; j < 8; j++)                         \
        gl_lds16(srcp[j] + (s) * 64, bq_ + dstp[j]);                      \
  }

  // ---- frag read offsets (ushort units) ----
  // row = R0+(l&31) (R0 mult of 32 -> row&7 = l&7); hi piece p = 2*(l>>5) (kk=0);
  // stored p' = p ^ (l&7). lo = ^8; kk=1 = ^32.
  const int p0 = ((2 * (l >> 5)) ^ (l & 7)) * 8;
  int aoff[4], boff[2];
#pragma unroll
  for (int m = 0; m < 4; m++) aoff[m] = (wr * 128 + m * 32 + (l & 31)) * 64 + p0;
#pragma unroll
  for (int n = 0; n < 2; n++) boff[n] = 16384 + (wc * 64 + n * 32 + (l & 31)) * 64 + p0;

  f32x16 acc[4][2] = {};
  bf16x8 ah[4], al[4], bh0, bl0, bh1, bl1;

#define PH()                                                              \
  __builtin_amdgcn_s_barrier();                                           \
  asm volatile("s_waitcnt lgkmcnt(0)" ::: "memory");                      \
  __builtin_amdgcn_sched_barrier(0);

#define M6(MI, BH, BL, NI)                                                \
  __builtin_amdgcn_s_setprio(1);                                          \
  acc[MI][NI] = MFMA32(ah[MI], BH, acc[MI][NI], 0, 0, 0);                 \
  acc[MI][NI] = MFMA32(al[MI], BH, acc[MI][NI], 0, 0, 0);                 \
  acc[MI][NI] = MFMA32(ah[MI], BL, acc[MI][NI], 0, 0, 0);                 \
  acc[MI + 1][NI] = MFMA32(ah[MI + 1], BH, acc[MI + 1][NI], 0, 0, 0);     \
  acc[MI + 1][NI] = MFMA32(al[MI + 1], BH, acc[MI + 1][NI], 0, 0, 0);     \
  acc[MI + 1][NI] = MFMA32(ah[MI + 1], BL, acc[MI + 1][NI], 0, 0, 0);     \
  __builtin_amdgcn_s_setprio(0);                                          \
  __builtin_amdgcn_sched_barrier(0);

  STG(0);

  for (int s = 0; s < NS; ++s) {
    // gate: own stage(s) landed (issued a full step ago -> free); barrier
    // publishes all waves' stages + certifies slot (s+1)&1 fully read.
    asm volatile("s_waitcnt vmcnt(0)" ::: "memory");
    __builtin_amdgcn_s_barrier();
    __builtin_amdgcn_sched_barrier(0);
    if (s + 1 < NS) STG(s + 1);
    const unsigned short* bq = lds + (s & 1) * 32768;

    // P0: read A01 k0 + B0 k0 | MFMA m01 n0 k0
    ah[0] = *(const bf16x8*)(bq + aoff[0]);
    al[0] = *(const bf16x8*)(bq + (aoff[0] ^ 8));
    ah[1] = *(const bf16x8*)(bq + aoff[1]);
    al[1] = *(const bf16x8*)(bq + (aoff[1] ^ 8));
    bh0 = *(const bf16x8*)(bq + boff[0]);
    bl0 = *(const bf16x8*)(bq + (boff[0] ^ 8));
    PH()
    M6(0, bh0, bl0, 0)
    // P1: read A23 k0 | MFMA m23 n0 k0
    ah[2] = *(const bf16x8*)(bq + aoff[2]);
    al[2] = *(const bf16x8*)(bq + (aoff[2] ^ 8));
    ah[3] = *(const bf16x8*)(bq + aoff[3]);
    al[3] = *(const bf16x8*)(bq + (aoff[3] ^ 8));
    PH()
    M6(2, bh0, bl0, 0)
    // P2: read B1 k0 | MFMA m01 n1 k0
    bh1 = *(const bf16x8*)(bq + boff[1]);
    bl1 = *(const bf16x8*)(bq + (boff[1] ^ 8));
    PH()
    M6(0, bh1, bl1, 1)
    // P3: read A01 k1 + B0 k1 | MFMA m23 n1 k0
    ah[0] = *(const bf16x8*)(bq + (aoff[0] ^ 32));
    al[0] = *(const bf16x8*)(bq + (aoff[0] ^ 40));
    ah[1] = *(const bf16x8*)(bq + (aoff[1] ^ 32));
    al[1] = *(const bf16x8*)(bq + (aoff[1] ^ 40));
    bh0 = *(const bf16x8*)(bq + (boff[0] ^ 32));
    bl0 = *(const bf16x8*)(bq + (boff[0] ^ 40));
    PH()
    M6(2, bh1, bl1, 1)
    // P4: read A23 k1 | MFMA m01 n0 k1
    ah[2] = *(const bf16x8*)(bq + (aoff[2] ^ 32));
    al[2] = *(const bf16x8*)(bq + (aoff[2] ^ 40));
    ah[3] = *(const bf16x8*)(bq + (aoff[3] ^ 32));
    al[3] = *(const bf16x8*)(bq + (aoff[3] ^ 40));
    PH()
    M6(0, bh0, bl0, 0)
    // P5: read B1 k1 | MFMA m23 n0 k1
    bh1 = *(const bf16x8*)(bq + (boff[1] ^ 32));
    bl1 = *(const bf16x8*)(bq + (boff[1] ^ 40));
    PH()
    M6(2, bh0, bl0, 0)
    // P6: MFMA m01 n1 k1 + m23 n1 k1
    PH()
    M6(0, bh1, bl1, 1)
    M6(2, bh1, bl1, 1)
  }
#undef STG
#undef PH
#undef M6

  // epilogue (R11/R16 verbatim): C/D 32x32: col = l&31, row = (r&3)+8*(r>>2)+4*(l>>5)
#pragma unroll
  for (int m = 0; m < 4; m++)
#pragma unroll
    for (int n = 0; n < 2; n++) {
      const int col = colB0 + wc * 64 + n * 32 + (l & 31);
      const float bv = bias[col];
      const int cofs = (col >> 3) * 16 + (col & 7);
#pragma unroll
      for (int r = 0; r < 16; r++) {
        const long row = rowA0 + wr * 128 + m * 32 + (r & 3) + 8 * (r >> 2) + 4 * (l >> 5);
        float xv = acc[m][n][r] + bv;
        if (ACT) xv = fmaxf(xv, 0.0f);
        const unsigned short h = f2bf_rne(xv);
        unsigned short* cp = C + row * 1024 + cofs;
        cp[0] = h;
        cp[8] = f2bf_rne(xv - bf2f(h));
      }
    }
}

// dots[b,64,1024] = scale * slots[64,512] @ k[b,1024,512]^T  (interleaved split in)
__global__ __launch_bounds__(256) void gemm_dots_split(
    const unsigned short* __restrict__ QI, const unsigned short* __restrict__ KI,
    float* __restrict__ dots) {
  constexpr int K = 512, BM = 64, BN = 128, BK = 32;
  __shared__ __align__(16) unsigned short lah[BM * BK];
  __shared__ __align__(16) unsigned short lal[BM * BK];
  __shared__ __align__(16) unsigned short lbh[BN * BK];
  __shared__ __align__(16) unsigned short lbl[BN * BK];
  const int t = threadIdx.x, l = t & 63, w = t >> 6;
  const int b = blockIdx.x >> 3, bc = blockIdx.x & 7;
  const unsigned short* kb = KI + (long)b * Nn * 1024;
  f32x4 acc[4][2] = {};

  const int qbase = (t >> 2) * 1024 + (t & 3) * 16;
  const long kbase0 = (long)(bc * BN + (t >> 2)) * 1024 + (t & 3) * 16;
  const long kbase1 = (long)(bc * BN + 64 + (t >> 2)) * 1024 + (t & 3) * 16;

  for (int k0 = 0; k0 < K; k0 += BK) {
    const int ko = k0 * 2;  // ushort offset of granule (k0>>3)*16
    const int lo = w * 512;
    gl_lds16(QI + qbase + ko, lah + lo);
    gl_lds16(QI + qbase + ko + 8, lal + lo);
    gl_lds16(kb + kbase0 + ko, lbh + lo);
    gl_lds16(kb + kbase0 + ko + 8, lbl + lo);
    gl_lds16(kb + kbase1 + ko, lbh + 2048 + lo);
    gl_lds16(kb + kbase1 + ko + 8, lbl + 2048 + lo);
    __syncthreads();
    bf16x8 ah[4], al[4], bh[2], bl[2];
#pragma unroll
    for (int m = 0; m < 4; m++) {
      const int off = (m * 16 + (l & 15)) * BK + (l >> 4) * 8;
      ah[m] = *(const bf16x8*)(lah + off);
      al[m] = *(const bf16x8*)(lal + off);
    }
#pragma unroll
    for (int n = 0; n < 2; n++) {
      const int off = (w * 32 + n * 16 + (l & 15)) * BK + (l >> 4) * 8;
      bh[n] = *(const bf16x8*)(lbh + off);
      bl[n] = *(const bf16x8*)(lbl + off);
    }
#pragma unroll
    for (int m = 0; m < 4; m++)
#pragma unroll
      for (int n = 0; n < 2; n++) {
        acc[m][n] = __builtin_amdgcn_mfma_f32_16x16x32_bf16(ah[m], bh[n], acc[m][n], 0, 0, 0);
        acc[m][n] = __builtin_amdgcn_mfma_f32_16x16x32_bf16(al[m], bh[n], acc[m][n], 0, 0, 0);
        acc[m][n] = __builtin_amdgcn_mfma_f32_16x16x32_bf16(ah[m], bl[n], acc[m][n], 0, 0, 0);
      }
    __syncthreads();
  }
  float* dp = dots + (long)b * Ss * Nn;
#pragma unroll
  for (int m = 0; m < 4; m++) {
    const int row = m * 16 + (l >> 4) * 4;
#pragma unroll
    for (int n = 0; n < 2; n++) {
      const int col = bc * BN + w * 32 + n * 16 + (l & 15);
#pragma unroll
      for (int r = 0; r < 4; r++) dp[(long)(row + r) * Nn + col] = acc[m][n][r] * kScale;
    }
  }
}

// per-batch: s_j[b,i] = sum_j dots, s_all[b] = sum_ij dots (coalesced float4 + shfl)
__global__ __launch_bounds__(256) void reduce_k(
    const float* __restrict__ dots, float* __restrict__ s_j, float* __restrict__ s_all) {
  const int b = blockIdx.x, t = threadIdx.x, l = t & 63, w = t >> 6;
  const float4* dp = (const float4*)(dots + (long)b * Ss * Nn);
  __shared__ float rowacc[64][4];
  __shared__ float rowsum[64];
  for (int r = 0; r < 64; ++r) {
    const float4 v = dp[r * 256 + t];
    float s = v.x + v.y + v.z + v.w;
#pragma unroll
    for (int off = 32; off; off >>= 1) s += __shfl_down(s, off);
    if (l == 0) rowacc[r][w] = s;
  }
  __syncthreads();
  if (t < 64) {
    const float v = rowacc[t][0] + rowacc[t][1] + rowacc[t][2] + rowacc[t][3];
    rowsum[t] = v;
    s_j[b * 64 + t] = v;
  }
  __syncthreads();
  if (t < 64) {
    float v = rowsum[t];
#pragma unroll
    for (int off = 32; off; off >>= 1) v += __shfl_down(v, off);
    if (t == 0) s_all[b] = v;
  }
}

// attn = sigmoid(dots * s_all/s_j) -> out; inv_r = 1/(rowsum(attn)+eps)
__global__ __launch_bounds__(256) void attn_k(
    const float* __restrict__ dots, const float* __restrict__ s_j,
    const float* __restrict__ s_all, float* __restrict__ attn_out,
    float* __restrict__ inv_r) {
  const int bi = blockIdx.x;
  const int b = bi >> 6;
  const int t = threadIdx.x;
  const float ratio = s_all[b] / s_j[bi];
  const float* dp = dots + (long)bi * Nn;
  float* ap = attn_out + (long)bi * Nn;
  float s = 0.f;
#pragma unroll
  for (int qq = 0; qq < 4; qq++) {
    const int j = qq * 256 + t;
    const float x = dp[j] * ratio;
    const float a = 1.f / (1.f + expf(-x));
    ap[j] = a;
    s += a;
  }
  __shared__ float red[256];
  red[t] = s;
  __syncthreads();
  for (int off = 128; off > 0; off >>= 1) {
    if (t < off) red[t] += red[t + off];
    __syncthreads();
  }
  if (t == 0) inv_r[bi] = 1.f / (red[0] + kEps);
}

// updates[b,i,d] = inv_r[b,i] * sum_j attn[b,i,j] * inputs[b,j,d]  (fp32 register tile)
__global__ __launch_bounds__(256, 1) void updates_k2(
    const float* __restrict__ attn, const float* __restrict__ inputs,
    const float* __restrict__ inv_r, float* __restrict__ out0) {
  constexpr int NT2 = 32;
  constexpr int BUF_F = 10240;
  extern __shared__ float ldsf[];
  const int t = threadIdx.x, lam = t & 63, w = t >> 6;
  const int b = blockIdx.x >> 1, dt = blockIdx.x & 1;
  const int ig = t >> 5, dg = t & 31;
  const float* inb = inputs + (size_t)b * (Nn * Dd) + dt * 256;
  const float* attsrc = attn + (size_t)b * (Ss * Nn) + (size_t)(t >> 2) * Nn + (t & 3) * 8;
  float acc[8][8] = {};
  float4 ga0, ga1, gb0, gb1;

#define UISSUE(bufi, tile, G0, G1)                                        \
  {                                                                       \
    const int j0_ = (tile)*32;                                            \
    G0 = *(const float4*)(attsrc + j0_);                                  \
    G1 = *(const float4*)(attsrc + j0_ + 4);                              \
    float* db_ = ldsf + (bufi)*BUF_F;                                     \
    _Pragma("unroll") for (int i_ = 0; i_ < 8; i_++) {                    \
      const int row_ = i_ * 4 + w;                                        \
      gl_lds16(inb + (size_t)(j0_ + row_) * Dd + lam * 4, db_ + row_ * 256); \
    }                                                                     \
  }

#define UWRITE(bufi, G0, G1)                                              \
  {                                                                       \
    float* ab_ = ldsf + (bufi)*BUF_F + 8192;                              \
    const int col_ = t >> 2;                                              \
    const int r0_ = (t & 3) * 8;                                          \
    ab_[(r0_ + 0) * 64 + col_] = G0.x;                                    \
    ab_[(r0_ + 1) * 64 + col_] = G0.y;                                    \
    ab_[(r0_ + 2) * 64 + col_] = G0.z;                                    \
    ab_[(r0_ + 3) * 64 + col_] = G0.w;                                    \
    ab_[(r0_ + 4) * 64 + col_] = G1.x;                                    \
    ab_[(r0_ + 5) * 64 + col_] = G1.y;                                    \
    ab_[(r0_ + 6) * 64 + col_] = G1.z;                                    \
    ab_[(r0_ + 7) * 64 + col_] = G1.w;                                    \
  }

#define UCOMP(bufi)                                                       \
  {                                                                       \
    const float* db_ = ldsf + (bufi)*BUF_F;                               \
    const float* ab_ = db_ + 8192;                                        \
    _Pragma("unroll 4") for (int jj = 0; jj < 32; jj++) {                 \
      float av[8], vv[8];                                                 \
      *(float4*)&av[0] = *(const float4*)(ab_ + jj * 64 + ig * 8);        \
      *(float4*)&av[4] = *(const float4*)(ab_ + jj * 64 + ig * 8 + 4);    \
      *(float4*)&vv[0] = *(const float4*)(db_ + jj * 256 + dg * 8);       \
      *(float4*)&vv[4] = *(const float4*)(db_ + jj * 256 + dg * 8 + 4);   \
      _Pragma("unroll") for (int m_ = 0; m_ < 8; m_++)                    \
          _Pragma("unroll") for (int n_ = 0; n_ < 8; n_++)                \
              acc[m_][n_] = __builtin_fmaf(av[m_], vv[n_], acc[m_][n_]);  \
    }                                                                     \
  }

  UISSUE(0, 0, ga0, ga1);
  UISSUE(1, 1, gb0, gb1);
  UWRITE(0, ga0, ga1);

  for (int tt = 0; tt < NT2; tt += 2) {
    asm volatile("s_waitcnt vmcnt(10)" ::: "memory");
    UWRITE((tt + 1) % 3, gb0, gb1);
    asm volatile("s_waitcnt lgkmcnt(0)" ::: "memory");
    __builtin_amdgcn_s_barrier();
    __builtin_amdgcn_sched_barrier(0);
    if (tt < NT2 - 2) UISSUE((tt + 2) % 3, tt + 2, ga0, ga1);
    UCOMP(tt % 3);
    if (tt + 1 < NT2 - 1) {
      asm volatile("s_waitcnt vmcnt(10)" ::: "memory");
    } else {
      asm volatile("s_waitcnt vmcnt(0)" ::: "memory");
    }
    if (tt + 1 < NT2 - 1) UWRITE((tt + 2) % 3, ga0, ga1);
    asm volatile("s_waitcnt lgkmcnt(0)" ::: "memory");
    __builtin_amdgcn_s_barrier();
    __builtin_amdgcn_sched_barrier(0);
    if (tt + 1 < NT2 - 2) UISSUE((tt + 3) % 3, tt + 3, gb0, gb1);
    UCOMP((tt + 1) % 3);
  }
#undef UISSUE
#undef UWRITE
#undef UCOMP

#pragma unroll
  for (int m = 0; m < 8; m++) {
    const int i = ig * 8 + m;
    const float ir = inv_r[b * 64 + i];
    float4 o0, o1;
    o0.x = acc[m][0] * ir; o0.y = acc[m][1] * ir; o0.z = acc[m][2] * ir; o0.w = acc[m][3] * ir;
    o1.x = acc[m][4] * ir; o1.y = acc[m][5] * ir; o1.z = acc[m][6] * ir; o1.w = acc[m][7] * ir;
    float* op = out0 + (size_t)(b * 64 + i) * Dd + dt * 256 + dg * 8;
    *(float4*)op = o0;
    *(float4*)(op + 4) = o1;
  }
}

extern "C" void kernel_launch(void* const* d_in, const int* in_sizes, int n_in,
                              void* d_out, int out_size, void* d_ws, size_t ws_size,
                              hipStream_t stream) {
  (void)in_sizes; (void)n_in; (void)out_size; (void)ws_size;
  const float* inputs_pe = (const float*)d_in[0];
  const float* inputs = (const float*)d_in[1];
  const float* slots = (const float*)d_in[2];
  const float* W1 = (const float*)d_in[3];
  const float* b1 = (const float*)d_in[4];
  const float* W2 = (const float*)d_in[5];
  const float* b2 = (const float*)d_in[6];
  const float* W3 = (const float*)d_in[7];
  const float* b3 = (const float*)d_in[8];

  char* ws = (char*)d_ws;
  size_t off = 0;
  auto alloc = [&](size_t bytes) -> void* {
    void* p = ws + off;
    off += (bytes + 255) & ~(size_t)255;
    return p;
  };
  const size_t actB = (size_t)Bb * Nn * 1024 * 2;  // interleaved split activation
  unsigned short* AI = (unsigned short*)alloc(actB);
  unsigned short* BI = (unsigned short*)alloc(actB);
  unsigned short* w1i = (unsigned short*)alloc(Dd * 1024 * 2);
  unsigned short* w2i = (unsigned short*)alloc(Dd * 1024 * 2);
  unsigned short* w3i = (unsigned short*)alloc(Dd * 1024 * 2);
  unsigned short* qi = (unsigned short*)alloc(Ss * 1024 * 2);
  float* dotsb = (float*)alloc((size_t)Bb * Ss * Nn * 4);
  float* s_j = (float*)alloc(Bb * Ss * 4);
  float* s_all = (float*)alloc(Bb * 4);
  float* inv_r = (float*)alloc(Bb * Ss * 4);

  float* out_updates = (float*)d_out;
  float* out_attn = out_updates + (size_t)Bb * Ss * Dd;

  const int kLdsG = 2 * 64 * 1024;  // 128KB ring-2 (64KB slots) for gemm_g2
  const int kLdsU = 3 * 40 * 1024;  // 120KB for updates_k2
  hipFuncSetAttribute(reinterpret_cast<const void*>(gemm_g2<1>),
                      hipFuncAttributeMaxDynamicSharedMemorySize, kLdsG);
  hipFuncSetAttribute(reinterpret_cast<const void*>(gemm_g2<0>),
                      hipFuncAttributeMaxDynamicSharedMemorySize, kLdsG);
  hipFuncSetAttribute(reinterpret_cast<const void*>(updates_k2),
                      hipFuncAttributeMaxDynamicSharedMemorySize, kLdsU);

  cast_split_i<<<4096, 256, 0, stream>>>(inputs_pe, AI, Bb * Nn * Dd / 8);
  cast_split_i<<<128, 256, 0, stream>>>(W1, w1i, Dd * Dd / 8);
  cast_split_i<<<128, 256, 0, stream>>>(W2, w2i, Dd * Dd / 8);
  cast_split_i<<<128, 256, 0, stream>>>(W3, w3i, Dd * Dd / 8);
  cast_split_i<<<16, 256, 0, stream>>>(slots, qi, Ss * Dd / 8);

  gemm_g2<1><<<1024, 512, kLdsG, stream>>>(AI, w1i, b1, BI);
  gemm_g2<1><<<1024, 512, kLdsG, stream>>>(BI, w2i, b2, AI);
  gemm_g2<0><<<1024, 512, kLdsG, stream>>>(AI, w3i, b3, BI);

  gemm_dots_split<<<Bb * 8, 256, 0, stream>>>(qi, BI, dotsb);
  reduce_k<<<Bb, 256, 0, stream>>>(dotsb, s_j, s_all);
  attn_k<<<Bb * Ss, 256, 0, stream>>>(dotsb, s_j, s_all, out_attn, inv_r);
  updates_k2<<<Bb * 2, 256, kLdsU, stream>>>(out_attn, inputs, inv_r, out_updates);
}

// Round 18
// 1021.537 us; speedup vs baseline: 1.2149x; 1.0180x over previous
//
#include <hip/hip_runtime.h>
#include <stdint.h>

#define Bb 128
#define Nn 1024
#define Dd 512
#define Ss 64

constexpr float kScale = 0.044194173824159216f;  // 512^-0.5
constexpr float kEps = 1e-8f;

typedef __bf16 bf16x8 __attribute__((ext_vector_type(8)));
typedef float f32x4 __attribute__((ext_vector_type(4)));
typedef float f32x16 __attribute__((ext_vector_type(16)));
typedef unsigned short ushort8 __attribute__((ext_vector_type(8)));

#define MFMA32 __builtin_amdgcn_mfma_f32_32x32x16_bf16

__device__ inline unsigned short f2bf_rne(float x) {
  unsigned u = __builtin_bit_cast(unsigned, x);
  u += 0x7FFFu + ((u >> 16) & 1u);
  return (unsigned short)(u >> 16);
}
__device__ inline float bf2f(unsigned short h) {
  unsigned u = ((unsigned)h) << 16;
  return __builtin_bit_cast(float, u);
}

// async global->LDS, 16B per lane; LDS dest must be wave-uniform base (HW adds lane*16)
__device__ inline void gl_lds16(const void* g, void* l) {
  typedef unsigned int u32;
  auto gp = (u32 __attribute__((address_space(1)))*)(unsigned long long)(uintptr_t)g;
  auto lp = (u32 __attribute__((address_space(3)))*)(unsigned int)(uintptr_t)l;
  __builtin_amdgcn_global_load_lds(gp, lp, 16, 0, 0);
}

// f32 -> INTERLEAVED split bf16: out[granule*16 + 0..7] = hi, [+8..15] = lo.
__global__ void cast_split_i(const float* __restrict__ in,
                             unsigned short* __restrict__ out, int n8) {
  int i = blockIdx.x * blockDim.x + threadIdx.x;
  const int stride = gridDim.x * blockDim.x;
  for (; i < n8; i += stride) {
    const float4 v0 = ((const float4*)in)[i * 2];
    const float4 v1 = ((const float4*)in)[i * 2 + 1];
    float f[8] = {v0.x, v0.y, v0.z, v0.w, v1.x, v1.y, v1.z, v1.w};
    ushort8 h, lo;
#pragma unroll
    for (int j = 0; j < 8; j++) {
      h[j] = f2bf_rne(f[j]);
      lo[j] = f2bf_rne(f[j] - bf2f(h[j]));
    }
    ((ushort8*)out)[i * 2] = h;
    ((ushort8*)out)[i * 2 + 1] = lo;
  }
}

// C[M,512] = act(A[M,512] @ W[512,512]^T + bias) — gemm_g2 from R17 (verbatim).
template <int ACT>
__global__ __launch_bounds__(512, 1) void gemm_g2(
    const unsigned short* __restrict__ A, const unsigned short* __restrict__ W,
    const float* __restrict__ bias, unsigned short* __restrict__ C) {
  constexpr int NS = 16;  // K=512 / 32
  extern __shared__ unsigned short lds[];  // 2 x 32768 ushorts = 128KB
  const int t = threadIdx.x, l = t & 63, w = t >> 6;
  const int wr = w >> 2, wc = w & 3;

  const int wg = ((blockIdx.x & 7) << 7) + (blockIdx.x >> 3);
  const long rowA0 = (long)(wg >> 1) * 256;
  const int colB0 = (wg & 1) * 256;

  const unsigned short* base8 = (w < 4) ? A + rowA0 * 1024 : W + (long)colB0 * 1024;
  const int qs = (l & 7) ^ ((l >> 3) & 7);
  const unsigned short* srcp[8];
  int dstp[8];
#pragma unroll
  for (int j = 0; j < 8; j++) {
    const int cl = (w & 3) * 8 + j;
    const int row = cl * 8 + (l >> 3);
    srcp[j] = base8 + (long)row * 1024 + qs * 8;
    dstp[j] = (w < 4 ? 0 : 16384) + cl * 512;
  }
#define STG(s)                                                            \
  {                                                                       \
    unsigned short* bq_ = lds + ((s) & 1) * 32768;                        \
    _Pragma("unroll") for (int j = 0; j < 8; j++)                         \
        gl_lds16(srcp[j] + (s) * 64, bq_ + dstp[j]);                      \
  }

  const int p0 = ((2 * (l >> 5)) ^ (l & 7)) * 8;
  int aoff[4], boff[2];
#pragma unroll
  for (int m = 0; m < 4; m++) aoff[m] = (wr * 128 + m * 32 + (l & 31)) * 64 + p0;
#pragma unroll
  for (int n = 0; n < 2; n++) boff[n] = 16384 + (wc * 64 + n * 32 + (l & 31)) * 64 + p0;

  f32x16 acc[4][2] = {};
  bf16x8 ah[4], al[4], bh0, bl0, bh1, bl1;

#define PH()                                                              \
  __builtin_amdgcn_s_barrier();                                           \
  asm volatile("s_waitcnt lgkmcnt(0)" ::: "memory");                      \
  __builtin_amdgcn_sched_barrier(0);

#define M6(MI, BH, BL, NI)                                                \
  __builtin_amdgcn_s_setprio(1);                                          \
  acc[MI][NI] = MFMA32(ah[MI], BH, acc[MI][NI], 0, 0, 0);                 \
  acc[MI][NI] = MFMA32(al[MI], BH, acc[MI][NI], 0, 0, 0);                 \
  acc[MI][NI] = MFMA32(ah[MI], BL, acc[MI][NI], 0, 0, 0);                 \
  acc[MI + 1][NI] = MFMA32(ah[MI + 1], BH, acc[MI + 1][NI], 0, 0, 0);     \
  acc[MI + 1][NI] = MFMA32(al[MI + 1], BH, acc[MI + 1][NI], 0, 0, 0);     \
  acc[MI + 1][NI] = MFMA32(ah[MI + 1], BL, acc[MI + 1][NI], 0, 0, 0);     \
  __builtin_amdgcn_s_setprio(0);                                          \
  __builtin_amdgcn_sched_barrier(0);

  STG(0);

  for (int s = 0; s < NS; ++s) {
    asm volatile("s_waitcnt vmcnt(0)" ::: "memory");
    __builtin_amdgcn_s_barrier();
    __builtin_amdgcn_sched_barrier(0);
    if (s + 1 < NS) STG(s + 1);
    const unsigned short* bq = lds + (s & 1) * 32768;

    ah[0] = *(const bf16x8*)(bq + aoff[0]);
    al[0] = *(const bf16x8*)(bq + (aoff[0] ^ 8));
    ah[1] = *(const bf16x8*)(bq + aoff[1]);
    al[1] = *(const bf16x8*)(bq + (aoff[1] ^ 8));
    bh0 = *(const bf16x8*)(bq + boff[0]);
    bl0 = *(const bf16x8*)(bq + (boff[0] ^ 8));
    PH()
    M6(0, bh0, bl0, 0)
    ah[2] = *(const bf16x8*)(bq + aoff[2]);
    al[2] = *(const bf16x8*)(bq + (aoff[2] ^ 8));
    ah[3] = *(const bf16x8*)(bq + aoff[3]);
    al[3] = *(const bf16x8*)(bq + (aoff[3] ^ 8));
    PH()
    M6(2, bh0, bl0, 0)
    bh1 = *(const bf16x8*)(bq + boff[1]);
    bl1 = *(const bf16x8*)(bq + (boff[1] ^ 8));
    PH()
    M6(0, bh1, bl1, 1)
    ah[0] = *(const bf16x8*)(bq + (aoff[0] ^ 32));
    al[0] = *(const bf16x8*)(bq + (aoff[0] ^ 40));
    ah[1] = *(const bf16x8*)(bq + (aoff[1] ^ 32));
    al[1] = *(const bf16x8*)(bq + (aoff[1] ^ 40));
    bh0 = *(const bf16x8*)(bq + (boff[0] ^ 32));
    bl0 = *(const bf16x8*)(bq + (boff[0] ^ 40));
    PH()
    M6(2, bh1, bl1, 1)
    ah[2] = *(const bf16x8*)(bq + (aoff[2] ^ 32));
    al[2] = *(const bf16x8*)(bq + (aoff[2] ^ 40));
    ah[3] = *(const bf16x8*)(bq + (aoff[3] ^ 32));
    al[3] = *(const bf16x8*)(bq + (aoff[3] ^ 40));
    PH()
    M6(0, bh0, bl0, 0)
    bh1 = *(const bf16x8*)(bq + (boff[1] ^ 32));
    bl1 = *(const bf16x8*)(bq + (boff[1] ^ 40));
    PH()
    M6(2, bh0, bl0, 0)
    PH()
    M6(0, bh1, bl1, 1)
    M6(2, bh1, bl1, 1)
  }
#undef STG
#undef PH
#undef M6

#pragma unroll
  for (int m = 0; m < 4; m++)
#pragma unroll
    for (int n = 0; n < 2; n++) {
      const int col = colB0 + wc * 64 + n * 32 + (l & 31);
      const float bv = bias[col];
      const int cofs = (col >> 3) * 16 + (col & 7);
#pragma unroll
      for (int r = 0; r < 16; r++) {
        const long row = rowA0 + wr * 128 + m * 32 + (r & 3) + 8 * (r >> 2) + 4 * (l >> 5);
        float xv = acc[m][n][r] + bv;
        if (ACT) xv = fmaxf(xv, 0.0f);
        const unsigned short h = f2bf_rne(xv);
        unsigned short* cp = C + row * 1024 + cofs;
        cp[0] = h;
        cp[8] = f2bf_rne(xv - bf2f(h));
      }
    }
}

// dots[b,64,1024] = scale * slots[64,512] @ k[b,1024,512]^T  (interleaved split in)
__global__ __launch_bounds__(256) void gemm_dots_split(
    const unsigned short* __restrict__ QI, const unsigned short* __restrict__ KI,
    float* __restrict__ dots) {
  constexpr int K = 512, BM = 64, BN = 128, BK = 32;
  __shared__ __align__(16) unsigned short lah[BM * BK];
  __shared__ __align__(16) unsigned short lal[BM * BK];
  __shared__ __align__(16) unsigned short lbh[BN * BK];
  __shared__ __align__(16) unsigned short lbl[BN * BK];
  const int t = threadIdx.x, l = t & 63, w = t >> 6;
  const int b = blockIdx.x >> 3, bc = blockIdx.x & 7;
  const unsigned short* kb = KI + (long)b * Nn * 1024;
  f32x4 acc[4][2] = {};

  const int qbase = (t >> 2) * 1024 + (t & 3) * 16;
  const long kbase0 = (long)(bc * BN + (t >> 2)) * 1024 + (t & 3) * 16;
  const long kbase1 = (long)(bc * BN + 64 + (t >> 2)) * 1024 + (t & 3) * 16;

  for (int k0 = 0; k0 < K; k0 += BK) {
    const int ko = k0 * 2;
    const int lo = w * 512;
    gl_lds16(QI + qbase + ko, lah + lo);
    gl_lds16(QI + qbase + ko + 8, lal + lo);
    gl_lds16(kb + kbase0 + ko, lbh + lo);
    gl_lds16(kb + kbase0 + ko + 8, lbl + lo);
    gl_lds16(kb + kbase1 + ko, lbh + 2048 + lo);
    gl_lds16(kb + kbase1 + ko + 8, lbl + 2048 + lo);
    __syncthreads();
    bf16x8 ah[4], al[4], bh[2], bl[2];
#pragma unroll
    for (int m = 0; m < 4; m++) {
      const int off = (m * 16 + (l & 15)) * BK + (l >> 4) * 8;
      ah[m] = *(const bf16x8*)(lah + off);
      al[m] = *(const bf16x8*)(lal + off);
    }
#pragma unroll
    for (int n = 0; n < 2; n++) {
      const int off = (w * 32 + n * 16 + (l & 15)) * BK + (l >> 4) * 8;
      bh[n] = *(const bf16x8*)(lbh + off);
      bl[n] = *(const bf16x8*)(lbl + off);
    }
#pragma unroll
    for (int m = 0; m < 4; m++)
#pragma unroll
      for (int n = 0; n < 2; n++) {
        acc[m][n] = __builtin_amdgcn_mfma_f32_16x16x32_bf16(ah[m], bh[n], acc[m][n], 0, 0, 0);
        acc[m][n] = __builtin_amdgcn_mfma_f32_16x16x32_bf16(al[m], bh[n], acc[m][n], 0, 0, 0);
        acc[m][n] = __builtin_amdgcn_mfma_f32_16x16x32_bf16(ah[m], bl[n], acc[m][n], 0, 0, 0);
      }
    __syncthreads();
  }
  float* dp = dots + (long)b * Ss * Nn;
#pragma unroll
  for (int m = 0; m < 4; m++) {
    const int row = m * 16 + (l >> 4) * 4;
#pragma unroll
    for (int n = 0; n < 2; n++) {
      const int col = bc * BN + w * 32 + n * 16 + (l & 15);
#pragma unroll
      for (int r = 0; r < 4; r++) dp[(long)(row + r) * Nn + col] = acc[m][n][r] * kScale;
    }
  }
}

// per-batch: s_j[b,i] = sum_j dots, s_all[b] = sum_ij dots (coalesced float4 + shfl)
__global__ __launch_bounds__(256) void reduce_k(
    const float* __restrict__ dots, float* __restrict__ s_j, float* __restrict__ s_all) {
  const int b = blockIdx.x, t = threadIdx.x, l = t & 63, w = t >> 6;
  const float4* dp = (const float4*)(dots + (long)b * Ss * Nn);
  __shared__ float rowacc[64][4];
  __shared__ float rowsum[64];
  for (int r = 0; r < 64; ++r) {
    const float4 v = dp[r * 256 + t];
    float s = v.x + v.y + v.z + v.w;
#pragma unroll
    for (int off = 32; off; off >>= 1) s += __shfl_down(s, off);
    if (l == 0) rowacc[r][w] = s;
  }
  __syncthreads();
  if (t < 64) {
    const float v = rowacc[t][0] + rowacc[t][1] + rowacc[t][2] + rowacc[t][3];
    rowsum[t] = v;
    s_j[b * 64 + t] = v;
  }
  __syncthreads();
  if (t < 64) {
    float v = rowsum[t];
#pragma unroll
    for (int off = 32; off; off >>= 1) v += __shfl_down(v, off);
    if (t == 0) s_all[b] = v;
  }
}

// attn = sigmoid(dots * s_all/s_j) -> out; inv_r = 1/(rowsum(attn)+eps)
__global__ __launch_bounds__(256) void attn_k(
    const float* __restrict__ dots, const float* __restrict__ s_j,
    const float* __restrict__ s_all, float* __restrict__ attn_out,
    float* __restrict__ inv_r) {
  const int bi = blockIdx.x;
  const int b = bi >> 6;
  const int t = threadIdx.x;
  const float ratio = s_all[b] / s_j[bi];
  const float* dp = dots + (long)bi * Nn;
  float* ap = attn_out + (long)bi * Nn;
  float s = 0.f;
#pragma unroll
  for (int qq = 0; qq < 4; qq++) {
    const int j = qq * 256 + t;
    const float x = dp[j] * ratio;
    const float a = 1.f / (1.f + expf(-x));
    ap[j] = a;
    s += a;
  }
  __shared__ float red[256];
  red[t] = s;
  __syncthreads();
  for (int off = 128; off > 0; off >>= 1) {
    if (t < off) red[t] += red[t + off];
    __syncthreads();
  }
  if (t == 0) inv_r[bi] = 1.f / (red[0] + kEps);
}

// updates[b,i,d] = inv_r[b,i] * sum_j attn[b,i,j] * inputs[b,j,d]
// R18: block = (b, dt in 0..3), cols dt*128..+127; 256 thr; thread tile 8i x 4d
// at d = dg*4 (vv float4 -> 4-way banks, was 8-way); av broadcast (free).
// Slot = in[32][128]f32 (16KB) @0 | attT[32][64] (8KB) @4096f; ring-3 = 72KB
// -> 2 blocks/CU (8 waves hides barriers). Pipeline = proven ring-3 order;
// 6 vm ops per UISSUE -> vmcnt(6)->0 tail.
__global__ __launch_bounds__(256) void updates_k6(
    const float* __restrict__ attn, const float* __restrict__ inputs,
    const float* __restrict__ inv_r, float* __restrict__ out0) {
  constexpr int NT2 = 32;      // 1024 / 32
  constexpr int BUF_F = 6144;  // floats per 24KB slot: in@0 (4096), attT@4096 (2048)
  extern __shared__ float ldsf[];
  const int t = threadIdx.x, l = t & 63, w = t >> 6;
  const int b = blockIdx.x >> 2, dt = blockIdx.x & 3;
  const int ig = t >> 5, dg = t & 31;
  const float* inb = inputs + (size_t)b * (Nn * Dd) + dt * 128;
  const float* attsrc = attn + (size_t)b * (Ss * Nn) + (size_t)(t >> 2) * Nn + (t & 3) * 8;
  float acc[8][4] = {};
  float4 ga0, ga1, gb0, gb1;

#define UISSUE(bufi, tile, G0, G1)                                        \
  {                                                                       \
    const int j0_ = (tile)*32;                                            \
    G0 = *(const float4*)(attsrc + j0_);                                  \
    G1 = *(const float4*)(attsrc + j0_ + 4);                              \
    float* db_ = ldsf + (bufi)*BUF_F;                                     \
    _Pragma("unroll") for (int i_ = 0; i_ < 4; i_++) {                    \
      const int row_ = i_ * 8 + w * 2 + (l >> 5);                         \
      gl_lds16(inb + (size_t)(j0_ + row_) * Dd + (l & 31) * 4,            \
               db_ + (i_ * 8 + w * 2) * 128);                             \
    }                                                                     \
  }

#define UWRITE(bufi, G0, G1)                                              \
  {                                                                       \
    float* ab_ = ldsf + (bufi)*BUF_F + 4096;                              \
    const int col_ = t >> 2;                                              \
    const int r0_ = (t & 3) * 8;                                          \
    ab_[(r0_ + 0) * 64 + col_] = G0.x;                                    \
    ab_[(r0_ + 1) * 64 + col_] = G0.y;                                    \
    ab_[(r0_ + 2) * 64 + col_] = G0.z;                                    \
    ab_[(r0_ + 3) * 64 + col_] = G0.w;                                    \
    ab_[(r0_ + 4) * 64 + col_] = G1.x;                                    \
    ab_[(r0_ + 5) * 64 + col_] = G1.y;                                    \
    ab_[(r0_ + 6) * 64 + col_] = G1.z;                                    \
    ab_[(r0_ + 7) * 64 + col_] = G1.w;                                    \
  }

#define UCOMP(bufi)                                                       \
  {                                                                       \
    const float* db_ = ldsf + (bufi)*BUF_F;                               \
    const float* ab_ = db_ + 4096;                                        \
    _Pragma("unroll 4") for (int jj = 0; jj < 32; jj++) {                 \
      float av[8];                                                        \
      float4 vv;                                                          \
      *(float4*)&av[0] = *(const float4*)(ab_ + jj * 64 + ig * 8);        \
      *(float4*)&av[4] = *(const float4*)(ab_ + jj * 64 + ig * 8 + 4);    \
      vv = *(const float4*)(db_ + jj * 128 + dg * 4);                     \
      _Pragma("unroll") for (int m_ = 0; m_ < 8; m_++) {                  \
        acc[m_][0] = __builtin_fmaf(av[m_], vv.x, acc[m_][0]);            \
        acc[m_][1] = __builtin_fmaf(av[m_], vv.y, acc[m_][1]);            \
        acc[m_][2] = __builtin_fmaf(av[m_], vv.z, acc[m_][2]);            \
        acc[m_][3] = __builtin_fmaf(av[m_], vv.w, acc[m_][3]);            \
      }                                                                   \
    }                                                                     \
  }

  UISSUE(0, 0, ga0, ga1);
  UISSUE(1, 1, gb0, gb1);
  UWRITE(0, ga0, ga1);

  for (int tt = 0; tt < NT2; tt += 2) {
    asm volatile("s_waitcnt vmcnt(6)" ::: "memory");
    UWRITE((tt + 1) % 3, gb0, gb1);
    asm volatile("s_waitcnt lgkmcnt(0)" ::: "memory");
    __builtin_amdgcn_s_barrier();
    __builtin_amdgcn_sched_barrier(0);
    if (tt < NT2 - 2) UISSUE((tt + 2) % 3, tt + 2, ga0, ga1);
    UCOMP(tt % 3);
    if (tt + 1 < NT2 - 1) {
      asm volatile("s_waitcnt vmcnt(6)" ::: "memory");
    } else {
      asm volatile("s_waitcnt vmcnt(0)" ::: "memory");
    }
    if (tt + 1 < NT2 - 1) UWRITE((tt + 2) % 3, ga0, ga1);
    asm volatile("s_waitcnt lgkmcnt(0)" ::: "memory");
    __builtin_amdgcn_s_barrier();
    __builtin_amdgcn_sched_barrier(0);
    if (tt + 1 < NT2 - 2) UISSUE((tt + 3) % 3, tt + 3, gb0, gb1);
    UCOMP((tt + 1) % 3);
  }
#undef UISSUE
#undef UWRITE
#undef UCOMP

#pragma unroll
  for (int m = 0; m < 8; m++) {
    const int i = ig * 8 + m;
    const float ir = inv_r[b * 64 + i];
    float4 o;
    o.x = acc[m][0] * ir; o.y = acc[m][1] * ir; o.z = acc[m][2] * ir; o.w = acc[m][3] * ir;
    float* op = out0 + (size_t)(b * 64 + i) * Dd + dt * 128 + dg * 4;
    *(float4*)op = o;
  }
}

extern "C" void kernel_launch(void* const* d_in, const int* in_sizes, int n_in,
                              void* d_out, int out_size, void* d_ws, size_t ws_size,
                              hipStream_t stream) {
  (void)in_sizes; (void)n_in; (void)out_size; (void)ws_size;
  const float* inputs_pe = (const float*)d_in[0];
  const float* inputs = (const float*)d_in[1];
  const float* slots = (const float*)d_in[2];
  const float* W1 = (const float*)d_in[3];
  const float* b1 = (const float*)d_in[4];
  const float* W2 = (const float*)d_in[5];
  const float* b2 = (const float*)d_in[6];
  const float* W3 = (const float*)d_in[7];
  const float* b3 = (const float*)d_in[8];

  char* ws = (char*)d_ws;
  size_t off = 0;
  auto alloc = [&](size_t bytes) -> void* {
    void* p = ws + off;
    off += (bytes + 255) & ~(size_t)255;
    return p;
  };
  const size_t actB = (size_t)Bb * Nn * 1024 * 2;  // interleaved split activation
  unsigned short* AI = (unsigned short*)alloc(actB);
  unsigned short* BI = (unsigned short*)alloc(actB);
  unsigned short* w1i = (unsigned short*)alloc(Dd * 1024 * 2);
  unsigned short* w2i = (unsigned short*)alloc(Dd * 1024 * 2);
  unsigned short* w3i = (unsigned short*)alloc(Dd * 1024 * 2);
  unsigned short* qi = (unsigned short*)alloc(Ss * 1024 * 2);
  float* dotsb = (float*)alloc((size_t)Bb * Ss * Nn * 4);
  float* s_j = (float*)alloc(Bb * Ss * 4);
  float* s_all = (float*)alloc(Bb * 4);
  float* inv_r = (float*)alloc(Bb * Ss * 4);

  float* out_updates = (float*)d_out;
  float* out_attn = out_updates + (size_t)Bb * Ss * Dd;

  const int kLdsG = 2 * 64 * 1024;  // 128KB ring-2 for gemm_g2
  const int kLdsU = 3 * 24 * 1024;  // 72KB ring-3 for updates_k6 -> 2 blocks/CU
  hipFuncSetAttribute(reinterpret_cast<const void*>(gemm_g2<1>),
                      hipFuncAttributeMaxDynamicSharedMemorySize, kLdsG);
  hipFuncSetAttribute(reinterpret_cast<const void*>(gemm_g2<0>),
                      hipFuncAttributeMaxDynamicSharedMemorySize, kLdsG);
  hipFuncSetAttribute(reinterpret_cast<const void*>(updates_k6),
                      hipFuncAttributeMaxDynamicSharedMemorySize, kLdsU);

  cast_split_i<<<4096, 256, 0, stream>>>(inputs_pe, AI, Bb * Nn * Dd / 8);
  cast_split_i<<<128, 256, 0, stream>>>(W1, w1i, Dd * Dd / 8);
  cast_split_i<<<128, 256, 0, stream>>>(W2, w2i, Dd * Dd / 8);
  cast_split_i<<<128, 256, 0, stream>>>(W3, w3i, Dd * Dd / 8);
  cast_split_i<<<16, 256, 0, stream>>>(slots, qi, Ss * Dd / 8);

  gemm_g2<1><<<1024, 512, kLdsG, stream>>>(AI, w1i, b1, BI);
  gemm_g2<1><<<1024, 512, kLdsG, stream>>>(BI, w2i, b2, AI);
  gemm_g2<0><<<1024, 512, kLdsG, stream>>>(AI, w3i, b3, BI);

  gemm_dots_split<<<Bb * 8, 256, 0, stream>>>(qi, BI, dotsb);
  reduce_k<<<Bb, 256, 0, stream>>>(dotsb, s_j, s_all);
  attn_k<<<Bb * Ss, 256, 0, stream>>>(dotsb, s_j, s_all, out_attn, inv_r);
  updates_k6<<<Bb * 4, 256, kLdsU, stream>>>(out_attn, inputs, inv_r, out_updates);
}